// Round 1
// baseline (3100.185 us; speedup 1.0000x reference)
//
#include <hip/hip_runtime.h>

#define H 128
#define W 128
#define BATCH 4
#define CIN 128
#define COUT 64
#define HW (H*W)

// K1: dilated 3x3 conv, Cin=128 -> Cout=64, +bias, *scale.
// grid (128 h, 2 ocg, 16 = d*4+b), block 256.
// thread: wlo = t&63 handles pixels {wlo, wlo+64}; q = t>>6 handles oc = ocg*32 + q*8 + [0,8)
__global__ __launch_bounds__(256) void k_branch_conv(
    const float* __restrict__ x,
    const float* __restrict__ w1, const float* __restrict__ b1,
    const float* __restrict__ w2, const float* __restrict__ b2,
    const float* __restrict__ w3, const float* __restrict__ b3,
    const float* __restrict__ w4, const float* __restrict__ b4,
    float* __restrict__ feats)
{
    int h = blockIdx.x;
    int ocg = blockIdx.y;
    int zb = blockIdx.z;        // d*4 + b
    int d = zb >> 2, b = zb & 3;
    const int dil = 2*d + 1;    // 1,3,5,7
    const float scale = (float)dil;
    const float* wt; const float* bs;
    if      (d==0){wt=w1;bs=b1;}
    else if (d==1){wt=w2;bs=b2;}
    else if (d==2){wt=w3;bs=b3;}
    else          {wt=w4;bs=b4;}

    __shared__ float xs[8][3][144];   // c-chunk x 3 rows x (128+2*dil<=142)
    __shared__ float ws[32][8][9];

    int t = threadIdx.x;
    int wlo = t & 63;
    int q = t >> 6;                   // wave-uniform
    int ocbase = ocg*32;

    float acc0[8], acc1[8];
    #pragma unroll
    for (int o=0;o<8;o++){acc0[o]=0.f;acc1[o]=0.f;}

    const int width = 128 + 2*dil;
    for (int c0 = 0; c0 < CIN; c0 += 8) {
        for (int idx = t; idx < 8*3*144; idx += 256) {
            int c  = idx / 432;
            int r  = idx % 432;
            int ky = r / 144;
            int col= r % 144;
            float v = 0.f;
            if (col < width) {
                int y  = h + (ky-1)*dil;
                int xc = col - dil;
                if (y >= 0 && y < H && xc >= 0 && xc < W)
                    v = x[((b*CIN + c0 + c)*H + y)*W + xc];
            }
            xs[c][ky][col] = v;
        }
        for (int idx = t; idx < 32*8*9; idx += 256) {
            int o = idx / 72;
            int r = idx % 72;
            ws[o][r/9][r%9] = wt[((ocbase + o)*CIN + c0 + r/9)*9 + (r%9)];
        }
        __syncthreads();
        #pragma unroll
        for (int c=0;c<8;c++)
          #pragma unroll
          for (int ky=0;ky<3;ky++)
            #pragma unroll
            for (int kx=0;kx<3;kx++){
              float xv0 = xs[c][ky][wlo + kx*dil];
              float xv1 = xs[c][ky][wlo + 64 + kx*dil];
              #pragma unroll
              for (int o=0;o<8;o++){
                float wv = ws[q*8+o][c][ky*3+kx];   // wave-uniform broadcast
                acc0[o] += wv*xv0;
                acc1[o] += wv*xv1;
              }
            }
        __syncthreads();
    }
    #pragma unroll
    for (int o=0;o<8;o++){
        int oc = ocbase + q*8 + o;
        float bias = bs[oc];
        float* dst = feats + ((zb*(long)COUT + oc)*H + h)*W;
        dst[wlo]      = (acc0[o] + bias)*scale;
        dst[wlo + 64] = (acc1[o] + bias)*scale;
    }
}

// K2: 3x3 conv pad=1, Cin=64 -> Cout=18 (offsets). grid (128 h, 1, 16 zb), block 256.
__global__ __launch_bounds__(256) void k_offset_conv(
    const float* __restrict__ feats,
    const float* __restrict__ pw, const float* __restrict__ pb,
    float* __restrict__ offs)
{
    int h = blockIdx.x;
    int zb = blockIdx.z;
    __shared__ float xs[8][3][132];
    __shared__ float ws[18][8][9];
    int t = threadIdx.x;
    int w = t & 127;
    int half = t >> 7;                 // wave-uniform
    float acc[9];
    #pragma unroll
    for (int j=0;j<9;j++) acc[j]=0.f;
    const float* fin = feats + (long)zb*COUT*HW;
    for (int c0=0;c0<COUT;c0+=8){
        for (int idx=t; idx<8*3*132; idx+=256){
            int c  = idx / 396;
            int r  = idx % 396;
            int ky = r / 132;
            int col= r % 132;
            float v = 0.f;
            if (col < 130){
                int y  = h + ky - 1;
                int xc = col - 1;
                if (y>=0 && y<H && xc>=0 && xc<W)
                    v = fin[(c0+c)*HW + y*W + xc];
            }
            xs[c][ky][col] = v;
        }
        for (int idx=t; idx<18*8*9; idx+=256){
            int o = idx / 72;
            int r = idx % 72;
            ws[o][r/9][r%9] = pw[(o*COUT + c0 + r/9)*9 + (r%9)];
        }
        __syncthreads();
        #pragma unroll
        for (int c=0;c<8;c++)
          #pragma unroll
          for (int ky=0;ky<3;ky++)
            #pragma unroll
            for (int kx=0;kx<3;kx++){
                float xv = xs[c][ky][w+kx];
                #pragma unroll
                for (int j=0;j<9;j++)
                    acc[j] += ws[half*9+j][c][ky*3+kx]*xv;
            }
        __syncthreads();
    }
    #pragma unroll
    for (int j=0;j<9;j++){
        int oc = half*9 + j;
        offs[((long)zb*18 + oc)*HW + h*W + w] = acc[j] + pb[oc];
    }
}

// K3: fused deform sampling + dw einsum (K=576) + db + 1x1 (cw) + cb + ReLU.
// grid (128 h, 1, 4 b), block 256. thread: p0=t&31 owns pixels p0+{0,32,64,96}; g=t>>5 owns oc=g*8+[0,8)
__global__ __launch_bounds__(256) void k_deform_fused(
    const float* __restrict__ feats,
    const float* __restrict__ offs,
    const float* __restrict__ dw, const float* __restrict__ db,
    const float* __restrict__ cw, const float* __restrict__ cb,
    float* __restrict__ out)
{
    int h = blockIdx.x;
    int b = blockIdx.z;
    int t = threadIdx.x;
    int p0 = t & 31;
    int g  = t >> 5;

    __shared__ float smem[13824];           // 55296 B
    float* cglt = smem;                     // [9][128]
    float* cgrb = cglt + 1152;
    float* cglb = cgrb + 1152;
    float* cgrt = cglb + 1152;
    unsigned* cyx0 = (unsigned*)(cgrt + 1152);  // (lt_y<<16)|lt_x
    unsigned* cyx1 = cyx0 + 1152;               // (rb_y<<16)|rb_x
    float* sam  = smem + 6912;              // [4 c][9 n][128 p]
    float* dwch = smem + 11520;             // [64 oc][4 c][9 n]
    // phase-4/5 overlays (sam/dwch/coords dead by then):
    float* def   = smem;                    // [128 p][65]
    float* cwlds = smem + 8320;             // [64 oc][64 o]

    float fin[4][8];
    #pragma unroll
    for (int k=0;k<4;k++)
      #pragma unroll
      for (int o=0;o<8;o++) fin[k][o]=0.f;

    for (int d=0; d<4; d++){
        int zb = d*4 + b;
        const float* fptr = feats + (long)zb*COUT*HW;
        const float* optr = offs + (long)zb*18*HW + h*W;

        __syncthreads();   // previous branch's def/cwlds reads done before coords overwrite
        for (int idx=t; idx<1152; idx+=256){
            int p = idx & 127;
            int n = idx >> 7;
            float offy = optr[n*HW + p];
            float offx = optr[(n+9)*HW + p];
            float py = (float)(h+1) + (float)(n/3 - 1) + offy;
            float px = (float)(p+1) + (float)(n%3 - 1) + offx;
            float fy = floorf(py), fx = floorf(px);
            float lty = fminf(fmaxf(fy,      0.f), 129.f);
            float ltx = fminf(fmaxf(fx,      0.f), 129.f);
            float rby = fminf(fmaxf(fy+1.f,  0.f), 129.f);
            float rbx = fminf(fmaxf(fx+1.f,  0.f), 129.f);
            float pyc = fminf(fmaxf(py,      0.f), 129.f);
            float pxc = fminf(fmaxf(px,      0.f), 129.f);
            cglt[idx] = (1.f + (lty - pyc))*(1.f + (ltx - pxc));
            cgrb[idx] = (1.f - (rby - pyc))*(1.f - (rbx - pxc));
            cglb[idx] = (1.f + (lty - pyc))*(1.f - (rbx - pxc));
            cgrt[idx] = (1.f - (rby - pyc))*(1.f + (ltx - pxc));
            cyx0[idx] = ((unsigned)(int)lty << 16) | (unsigned)(int)ltx;
            cyx1[idx] = ((unsigned)(int)rby << 16) | (unsigned)(int)rbx;
        }
        float acc[4][8];
        #pragma unroll
        for (int k=0;k<4;k++)
          #pragma unroll
          for (int o=0;o<8;o++) acc[k][o]=0.f;
        __syncthreads();

        for (int c0=0;c0<COUT;c0+=4){
            for (int idx=t; idx<2304; idx+=256){
                int o = idx/36; int r = idx%36;
                dwch[idx] = dw[(o*COUT + c0 + r/9)*9 + (r%9)];
            }
            #pragma unroll 2
            for (int i=0;i<18;i++){
                int j = (t>>7) + 2*i;           // 0..35
                int p = t & 127;
                int c = j/9, n = j%9;
                int cn = n*128 + p;
                unsigned yx0 = cyx0[cn], yx1 = cyx1[cn];
                int lty = yx0>>16, ltx = yx0 & 0xffff;
                int rby = yx1>>16, rbx = yx1 & 0xffff;
                const float* fc = fptr + (c0+c)*HW;
                float vlt = (lty>=1 && lty<=128 && ltx>=1 && ltx<=128) ? fc[(lty-1)*W + (ltx-1)] : 0.f;
                float vrb = (rby>=1 && rby<=128 && rbx>=1 && rbx<=128) ? fc[(rby-1)*W + (rbx-1)] : 0.f;
                float vlb = (lty>=1 && lty<=128 && rbx>=1 && rbx<=128) ? fc[(lty-1)*W + (rbx-1)] : 0.f;
                float vrt = (rby>=1 && rby<=128 && ltx>=1 && ltx<=128) ? fc[(rby-1)*W + (ltx-1)] : 0.f;
                sam[(c*9+n)*128 + p] = cglt[cn]*vlt + cgrb[cn]*vrb + cglb[cn]*vlb + cgrt[cn]*vrt;
            }
            __syncthreads();
            #pragma unroll
            for (int c=0;c<4;c++)
              #pragma unroll
              for (int n=0;n<9;n++){
                float s0 = sam[(c*9+n)*128 + p0];
                float s1 = sam[(c*9+n)*128 + p0+32];
                float s2 = sam[(c*9+n)*128 + p0+64];
                float s3 = sam[(c*9+n)*128 + p0+96];
                #pragma unroll
                for (int o=0;o<8;o++){
                  float wv = dwch[(g*8+o)*36 + c*9 + n];
                  acc[0][o]+=wv*s0; acc[1][o]+=wv*s1; acc[2][o]+=wv*s2; acc[3][o]+=wv*s3;
                }
              }
            __syncthreads();
        }
        // phase 4: stage deform output (+db) and this branch's cw slice
        #pragma unroll
        for (int k=0;k<4;k++)
          #pragma unroll
          for (int o=0;o<8;o++){
            int oc = g*8+o;
            def[(p0+32*k)*65 + oc] = acc[k][o] + db[oc];
          }
        for (int idx=t; idx<4096; idx+=256){
            int o = idx & 63; int oc = idx >> 6;
            cwlds[oc*64 + o] = cw[o*256 + d*64 + oc];
        }
        __syncthreads();
        // phase 5: 1x1 partial accumulation
        #pragma unroll 4
        for (int oc=0; oc<64; oc++){
            float s0 = def[(p0    )*65+oc];
            float s1 = def[(p0+32 )*65+oc];
            float s2 = def[(p0+64 )*65+oc];
            float s3 = def[(p0+96 )*65+oc];
            #pragma unroll
            for (int o=0;o<8;o++){
                float cv = cwlds[oc*64 + g*8+o];
                fin[0][o]+=cv*s0; fin[1][o]+=cv*s1; fin[2][o]+=cv*s2; fin[3][o]+=cv*s3;
            }
        }
    }
    #pragma unroll
    for (int k=0;k<4;k++)
      #pragma unroll
      for (int o=0;o<8;o++){
        int oc = g*8+o;
        float v = fin[k][o] + cb[oc];
        out[(((long)b*COUT + oc)*H + h)*W + p0 + 32*k] = fmaxf(v, 0.f);
      }
}

extern "C" void kernel_launch(void* const* d_in, const int* in_sizes, int n_in,
                              void* d_out, int out_size, void* d_ws, size_t ws_size,
                              hipStream_t stream) {
    const float* x  = (const float*)d_in[0];
    const float* w1 = (const float*)d_in[1];
    const float* b1 = (const float*)d_in[2];
    const float* w2 = (const float*)d_in[3];
    const float* b2 = (const float*)d_in[4];
    const float* w3 = (const float*)d_in[5];
    const float* b3 = (const float*)d_in[6];
    const float* w4 = (const float*)d_in[7];
    const float* b4 = (const float*)d_in[8];
    const float* pw = (const float*)d_in[9];
    const float* pb = (const float*)d_in[10];
    const float* dw = (const float*)d_in[11];
    const float* db = (const float*)d_in[12];
    const float* cw = (const float*)d_in[13];
    const float* cb = (const float*)d_in[14];
    float* out = (float*)d_out;

    float* feats = (float*)d_ws;                    // 16 * 64 * 16384 floats = 67.1 MB
    float* offs  = feats + 16ull*COUT*HW;           // 16 * 18 * 16384 floats = 18.9 MB

    k_branch_conv<<<dim3(128, 2, 16), 256, 0, stream>>>(x, w1,b1,w2,b2,w3,b3,w4,b4, feats);
    k_offset_conv<<<dim3(128, 1, 16), 256, 0, stream>>>(feats, pw, pb, offs);
    k_deform_fused<<<dim3(128, 1, 4), 256, 0, stream>>>(feats, offs, dw, db, cw, cb, out);
}

// Round 2
// 1549.359 us; speedup vs baseline: 2.0009x; 2.0009x over previous
//
#include <hip/hip_runtime.h>
#include <hip/hip_bf16.h>

#define H 128
#define W 128
#define CIN 128
#define COUT 64
#define HW (H*W)
#define HP 130
#define HPWP (130*130)

typedef __hip_bfloat16 bf16;

__device__ __forceinline__ float b2f(bf16 v){ return __bfloat162float(v); }
__device__ __forceinline__ bf16  f2b(float v){ return __float2bfloat16(v); }

// ---------------------------------------------------------------------------
// K1: dilated 3x3 conv Cin=128 -> Cout=64, (+bias)*scale, writes PADDED bf16
// feats [zb][64][130][130] with zero borders. grid (128 h, 16 zb), block 256.
// thread: p0=t&31 -> pixels p0+{0,32,64,96}; q=t>>5 -> oc = q*8+[0,8)
// ---------------------------------------------------------------------------
__global__ __launch_bounds__(256,4) void k_branch_conv(
    const float* __restrict__ x,
    const float* __restrict__ w1, const float* __restrict__ b1,
    const float* __restrict__ w2, const float* __restrict__ b2,
    const float* __restrict__ w3, const float* __restrict__ b3,
    const float* __restrict__ w4, const float* __restrict__ b4,
    bf16* __restrict__ feats)
{
    int h  = blockIdx.x;
    int zb = blockIdx.y;            // d*4 + b
    int d = zb >> 2, b = zb & 3;
    const int dil = 2*d + 1;        // 1,3,5,7
    const float scale = (float)dil;
    const float* wt; const float* bs;
    if      (d==0){wt=w1;bs=b1;}
    else if (d==1){wt=w2;bs=b2;}
    else if (d==2){wt=w3;bs=b3;}
    else          {wt=w4;bs=b4;}

    __shared__ float xs[8*3*144];   // [c][ky][col], stride 144
    __shared__ float ws2[8*9*64];   // [c*9+tap][64 oc]  -> b128 reads

    int t  = threadIdx.x;
    int p0 = t & 31;
    int q  = t >> 5;                // 0..7, half-wave uniform

    bf16* fbase = feats + (size_t)zb*COUT*HPWP;

    // zero padded borders (this block's row: cols 0 & 129; h==0 also rows 0 & 129)
    for (int idx=t; idx<2*COUT; idx+=256){
        int oc = idx>>1, side = idx&1;
        fbase[(size_t)oc*HPWP + (h+1)*HP + side*129] = f2b(0.f);
    }
    if (h==0){
        for (int idx=t; idx<2*COUT*HP; idx+=256){
            int col = idx % HP;
            int r   = idx / HP;
            int oc = r >> 1, side = r & 1;
            fbase[(size_t)oc*HPWP + side*129*HP + col] = f2b(0.f);
        }
    }

    float acc[4][8];
    #pragma unroll
    for (int k=0;k<4;k++)
      #pragma unroll
      for (int o=0;o<8;o++) acc[k][o]=0.f;

    const int width = 128 + 2*dil;
    for (int c0=0; c0<CIN; c0+=8){
        for (int idx=t; idx<3456; idx+=256){
            int c = idx/432, r = idx%432, ky = r/144, col = r%144;
            float v = 0.f;
            if (col < width){
                int y  = h + (ky-1)*dil;
                int xc = col - dil;
                if (y>=0 && y<H && xc>=0 && xc<W)
                    v = x[(((size_t)b*CIN + c0+c)*H + y)*W + xc];
            }
            xs[idx] = v;
        }
        for (int idx=t; idx<4608; idx+=256){
            int o = idx & 63, r = idx >> 6;   // r = c*9+tap, 0..71
            ws2[r*64 + o] = wt[((size_t)o*CIN + c0 + r/9)*9 + (r%9)];
        }
        __syncthreads();
        #pragma unroll
        for (int c=0;c<8;c++){
          #pragma unroll
          for (int ky=0;ky<3;ky++){
            #pragma unroll
            for (int kx=0;kx<3;kx++){
              const float* xr = &xs[(c*3+ky)*144 + p0 + kx*dil];
              float xv0 = xr[0], xv1 = xr[32], xv2 = xr[64], xv3 = xr[96];
              const float4* wp = (const float4*)&ws2[(c*9+ky*3+kx)*64 + q*8];
              float4 wa = wp[0], wb = wp[1];
              float wv[8] = {wa.x,wa.y,wa.z,wa.w,wb.x,wb.y,wb.z,wb.w};
              #pragma unroll
              for (int o=0;o<8;o++){
                acc[0][o] += wv[o]*xv0;
                acc[1][o] += wv[o]*xv1;
                acc[2][o] += wv[o]*xv2;
                acc[3][o] += wv[o]*xv3;
              }
            }
          }
        }
        __syncthreads();
    }
    #pragma unroll
    for (int o=0;o<8;o++){
        int oc = q*8+o;
        float bias = bs[oc];
        bf16* dst = fbase + (size_t)oc*HPWP + (h+1)*HP + 1;
        #pragma unroll
        for (int k=0;k<4;k++)
            dst[p0 + 32*k] = f2b((acc[k][o] + bias)*scale);
    }
}

// ---------------------------------------------------------------------------
// K2: 3x3 conv pad=1, 64 -> 18 (offsets) from padded bf16 feats (no bounds
// checks). grid (128 h, 16 zb), block 256. thread: w=t&127, half=t>>7 -> 9 oc.
// ---------------------------------------------------------------------------
__global__ __launch_bounds__(256,4) void k_offset_conv(
    const bf16* __restrict__ feats,
    const float* __restrict__ pw, const float* __restrict__ pb,
    bf16* __restrict__ offs)
{
    int h  = blockIdx.x;
    int zb = blockIdx.y;
    __shared__ float xs[8*3*132];   // [c][ky][col 0..129], stride 132
    __shared__ float ws2[8*9*24];   // [c*9+tap][half*12 + j], padded for b128
    int t = threadIdx.x;
    int w = t & 127;
    int half = t >> 7;              // wave-uniform
    float acc[9];
    #pragma unroll
    for (int j=0;j<9;j++) acc[j]=0.f;
    const bf16* fin = feats + (size_t)zb*COUT*HPWP;
    for (int c0=0; c0<COUT; c0+=8){
        for (int idx=t; idx<3120; idx+=256){
            int c = idx/390, r = idx%390, ky = r/130, col = r%130;
            xs[(c*3+ky)*132 + col] = b2f(fin[((size_t)(c0+c))*HPWP + (h+ky)*HP + col]);
        }
        for (int idx=t; idx<1296; idx+=256){
            int c = idx/162, r = idx%162, tap = r/18, o = r%18;
            ws2[(c*9+tap)*24 + (o/9)*12 + (o%9)] = pw[((size_t)o*COUT + c0+c)*9 + tap];
        }
        __syncthreads();
        #pragma unroll
        for (int c=0;c<8;c++)
          #pragma unroll
          for (int ky=0;ky<3;ky++)
            #pragma unroll
            for (int kx=0;kx<3;kx++){
               float xv = xs[(c*3+ky)*132 + w + kx];
               const float* wbase = &ws2[(c*9+ky*3+kx)*24 + half*12];
               float4 wa = *(const float4*)wbase;
               float4 wb = *(const float4*)(wbase+4);
               float w8 = wbase[8];
               acc[0]+=wa.x*xv; acc[1]+=wa.y*xv; acc[2]+=wa.z*xv; acc[3]+=wa.w*xv;
               acc[4]+=wb.x*xv; acc[5]+=wb.y*xv; acc[6]+=wb.z*xv; acc[7]+=wb.w*xv;
               acc[8]+=w8*xv;
            }
        __syncthreads();
    }
    #pragma unroll
    for (int j=0;j<9;j++){
        int oc = half*9+j;
        offs[((size_t)zb*18 + oc)*HW + h*W + w] = f2b(acc[j] + pb[oc]);
    }
}

// ---------------------------------------------------------------------------
// K3a: deformable sampling + dw einsum (K=576) + db for ONE branch.
// grid (128 h, 16 zb), block 256. Coords/coeffs precomputed once per row.
// thread: p0=t&31 -> pixels p0+{0,32,64,96}; g=t>>5 -> oc = g*8+[0,8)
// ---------------------------------------------------------------------------
__global__ __launch_bounds__(256,4) void k_deform(
    const bf16* __restrict__ feats,
    const bf16* __restrict__ offs,
    const float* __restrict__ dw, const float* __restrict__ db,
    bf16* __restrict__ dout)
{
    int h  = blockIdx.x;
    int zb = blockIdx.y;
    int t  = threadIdx.x;
    int p0 = t & 31;
    int g  = t >> 5;

    __shared__ unsigned lidx[1152];     // (lty*130+ltx) | dx<<17 | dy<<18
    __shared__ float coef[1152*4];      // g_lt, g_lb, g_rt, g_rb  (b128)
    __shared__ float sam[2*9*128];      // [c][n][p] for current 2-channel chunk
    __shared__ float dwch[18*64];       // [c*9+n][64 oc]          (b128)

    const bf16* obase = offs + (size_t)zb*18*HW + h*W;
    for (int idx=t; idx<1152; idx+=256){
        int p = idx & 127, n = idx >> 7;
        float offy = b2f(obase[n*HW + p]);
        float offx = b2f(obase[(n+9)*HW + p]);
        float py = (float)(h + n/3) + offy;        // (h+1) + (n/3-1)
        float px = (float)(p + n%3) + offx;        // (p+1) + (n%3-1)
        float fy = floorf(py), fx = floorf(px);
        float lty = fminf(fmaxf(fy,     0.f),129.f);
        float ltx = fminf(fmaxf(fx,     0.f),129.f);
        float rby = fminf(fmaxf(fy+1.f, 0.f),129.f);
        float rbx = fminf(fmaxf(fx+1.f, 0.f),129.f);
        float pyc = fminf(fmaxf(py,     0.f),129.f);
        float pxc = fminf(fmaxf(px,     0.f),129.f);
        float ay = 1.f + (lty-pyc), by = 1.f - (rby-pyc);
        float ax = 1.f + (ltx-pxc), bx = 1.f - (rbx-pxc);
        int ilty=(int)lty, iltx=(int)ltx;
        int dx = (int)rbx - iltx, dy = (int)rby - ilty;   // each in {0,1}
        lidx[idx] = (unsigned)(ilty*HP + iltx) | ((unsigned)dx<<17) | ((unsigned)dy<<18);
        coef[idx*4+0] = ay*ax;   // g_lt at (lty,ltx)
        coef[idx*4+1] = ay*bx;   // g_lb at (lty,rbx)
        coef[idx*4+2] = by*ax;   // g_rt at (rby,ltx)
        coef[idx*4+3] = by*bx;   // g_rb at (rby,rbx)
    }
    float acc[4][8];
    #pragma unroll
    for (int k=0;k<4;k++)
      #pragma unroll
      for (int o=0;o<8;o++) acc[k][o]=0.f;
    __syncthreads();

    const bf16* fbase = feats + (size_t)zb*COUT*HPWP;
    for (int c0=0; c0<COUT; c0+=2){
        for (int idx=t; idx<1152; idx+=256){
            int o = idx & 63, r = idx >> 6;      // r = c*9+n, 0..17
            dwch[r*64+o] = dw[((size_t)o*COUT + c0 + r/9)*9 + (r%9)];
        }
        #pragma unroll
        for (int i=0;i<9;i++){
            int idx = t + 256*i;                 // 2304 sample elements
            int p = idx & 127, cn = idx >> 7;    // cn 0..17
            int c = cn/9, n = cn - 9*c;
            int np = n*128 + p;
            unsigned u = lidx[np];
            int base = u & 0x1FFFF;
            int dx   = (u>>17)&1;
            int dyo  = ((u>>18)&1) ? HP : 0;
            const bf16* fc = fbase + (size_t)(c0+c)*HPWP;
            float vlt = b2f(fc[base]);
            float vlb = b2f(fc[base+dx]);
            float vrt = b2f(fc[base+dyo]);
            float vrb = b2f(fc[base+dyo+dx]);
            const float4 cf = *(const float4*)&coef[np*4];
            sam[cn*128+p] = cf.x*vlt + cf.y*vlb + cf.z*vrt + cf.w*vrb;
        }
        __syncthreads();
        #pragma unroll
        for (int cn=0;cn<18;cn++){
            float s0 = sam[cn*128+p0];
            float s1 = sam[cn*128+p0+32];
            float s2 = sam[cn*128+p0+64];
            float s3 = sam[cn*128+p0+96];
            const float4* wp = (const float4*)&dwch[cn*64 + g*8];
            float4 wa = wp[0], wb = wp[1];
            float wv[8] = {wa.x,wa.y,wa.z,wa.w,wb.x,wb.y,wb.z,wb.w};
            #pragma unroll
            for (int o=0;o<8;o++){
                acc[0][o]+=wv[o]*s0; acc[1][o]+=wv[o]*s1;
                acc[2][o]+=wv[o]*s2; acc[3][o]+=wv[o]*s3;
            }
        }
        __syncthreads();
    }
    #pragma unroll
    for (int o=0;o<8;o++){
        int oc = g*8+o;
        float bias = db[oc];
        bf16* dst = dout + ((size_t)zb*COUT + oc)*HW + h*W;
        #pragma unroll
        for (int k=0;k<4;k++)
            dst[p0+32*k] = f2b(acc[k][o] + bias);
    }
}

// ---------------------------------------------------------------------------
// K3b: 1x1 conv 256 -> 64 + cb + ReLU. grid (128 h, 4 b, 2 s), block 256.
// thread: p0=t&63 -> pixels {p0, p0+64}; q=t>>6 (wave-uniform) -> 8 oc.
// ---------------------------------------------------------------------------
__global__ __launch_bounds__(256,4) void k_combine(
    const bf16* __restrict__ dout,
    const float* __restrict__ cw, const float* __restrict__ cb,
    float* __restrict__ out)
{
    int h = blockIdx.x;
    int b = blockIdx.y;
    int s = blockIdx.z;
    int t = threadIdx.x;
    int p0 = t & 63;
    int q  = t >> 6;                 // wave-uniform
    __shared__ float cwl[64*32];     // [j 0..63][32 oc]  (b128, broadcast)
    float acc[2][8];
    #pragma unroll
    for (int k=0;k<2;k++)
      #pragma unroll
      for (int o=0;o<8;o++) acc[k][o]=0.f;

    for (int d=0; d<4; d++){
        for (int idx=t; idx<2048; idx+=256){
            int o32 = idx & 31, j = idx >> 5;
            cwl[j*32+o32] = cw[((size_t)(s*32+o32))*256 + d*64 + j];
        }
        __syncthreads();
        const bf16* dbase = dout + (size_t)((d*4+b)*COUT)*HW + h*W;
        #pragma unroll 8
        for (int jj=0; jj<64; jj++){
            float v0 = b2f(dbase[jj*HW + p0]);
            float v1 = b2f(dbase[jj*HW + p0+64]);
            const float4* wp = (const float4*)&cwl[jj*32 + q*8];
            float4 wa = wp[0], wb = wp[1];
            float wv[8] = {wa.x,wa.y,wa.z,wa.w,wb.x,wb.y,wb.z,wb.w};
            #pragma unroll
            for (int o=0;o<8;o++){
                acc[0][o]+=wv[o]*v0;
                acc[1][o]+=wv[o]*v1;
            }
        }
        __syncthreads();
    }
    #pragma unroll
    for (int o=0;o<8;o++){
        int oc = s*32 + q*8 + o;
        float bias = cb[oc];
        size_t base = (((size_t)b*COUT + oc)*H + h)*W;
        out[base + p0]      = fmaxf(acc[0][o]+bias, 0.f);
        out[base + p0 + 64] = fmaxf(acc[1][o]+bias, 0.f);
    }
}

extern "C" void kernel_launch(void* const* d_in, const int* in_sizes, int n_in,
                              void* d_out, int out_size, void* d_ws, size_t ws_size,
                              hipStream_t stream) {
    const float* x  = (const float*)d_in[0];
    const float* w1 = (const float*)d_in[1];
    const float* b1 = (const float*)d_in[2];
    const float* w2 = (const float*)d_in[3];
    const float* b2 = (const float*)d_in[4];
    const float* w3 = (const float*)d_in[5];
    const float* b3 = (const float*)d_in[6];
    const float* w4 = (const float*)d_in[7];
    const float* b4 = (const float*)d_in[8];
    const float* pw = (const float*)d_in[9];
    const float* pb = (const float*)d_in[10];
    const float* dw = (const float*)d_in[11];
    const float* db = (const float*)d_in[12];
    const float* cw = (const float*)d_in[13];
    const float* cb = (const float*)d_in[14];
    float* out = (float*)d_out;

    bf16* feats = (bf16*)d_ws;                          // 16*64*130*130 = 34.6 MB
    bf16* offs  = feats + (size_t)16*COUT*HPWP;         // 16*18*16384   =  9.4 MB
    bf16* doutb = offs  + (size_t)16*18*HW;             // 16*64*16384   = 33.6 MB

    k_branch_conv<<<dim3(128,16), 256, 0, stream>>>(x, w1,b1,w2,b2,w3,b3,w4,b4, feats);
    k_offset_conv<<<dim3(128,16), 256, 0, stream>>>(feats, pw, pb, offs);
    k_deform     <<<dim3(128,16), 256, 0, stream>>>(feats, offs, dw, db, doutb);
    k_combine    <<<dim3(128,4,2), 256, 0, stream>>>(doutb, cw, cb, out);
}

// Round 3
// 1116.274 us; speedup vs baseline: 2.7773x; 1.3880x over previous
//
#include <hip/hip_runtime.h>
#include <hip/hip_bf16.h>

#define H 128
#define W 128
#define CIN 128
#define COUT 64
#define HW (H*W)
// padded feats layout: [oc][y_pad 0..129][x: x_pad+3], row stride 136
#define HPX 136
#define HPWP (130*136)
// xt layout: [b][y+8 (144)][col+8 (144)][c 128] bf16
#define XTD 144

typedef __hip_bfloat16 bf16;
typedef __attribute__((ext_vector_type(8)))  short s16x8;
typedef __attribute__((ext_vector_type(16))) float f32x16;

__device__ __forceinline__ float b2f(bf16 v){ return __bfloat162float(v); }
__device__ __forceinline__ bf16  f2b(float v){ return __float2bfloat16(v); }
__device__ __forceinline__ unsigned pack2(float a, float b){
    unsigned short ua = __builtin_bit_cast(unsigned short, f2b(a));
    unsigned short ub = __builtin_bit_cast(unsigned short, f2b(b));
    return (unsigned)ua | ((unsigned)ub << 16);
}

// ---------------------------------------------------------------------------
// zero xt (21.2 MB) so xprep only fills the interior
// ---------------------------------------------------------------------------
__global__ __launch_bounds__(256) void k_zero(uint4* __restrict__ p, int n4){
    int stride = gridDim.x * 256;
    for (int i = blockIdx.x*256 + threadIdx.x; i < n4; i += stride)
        p[i] = make_uint4(0,0,0,0);
}

// ---------------------------------------------------------------------------
// wprep: wbt[d][tap][oc][c] bf16 from w_d[oc][c][tap] fp32. grid 576, block 256.
// ---------------------------------------------------------------------------
__global__ __launch_bounds__(256) void k_wprep(
    const float* __restrict__ w1, const float* __restrict__ w2,
    const float* __restrict__ w3, const float* __restrict__ w4,
    unsigned* __restrict__ wbt)
{
    int tid = blockIdx.x*256 + threadIdx.x;     // 147456 = 36*64*64
    int cpair = tid & 63;
    int oc    = (tid >> 6) & 63;
    int tapd  = tid >> 12;                       // 0..35
    int tap = tapd % 9, d = tapd / 9;
    const float* wt = (d==0)?w1:(d==1)?w2:(d==2)?w3:w4;
    float lo = wt[((size_t)oc*CIN + 2*cpair    )*9 + tap];
    float hi = wt[((size_t)oc*CIN + 2*cpair + 1)*9 + tap];
    wbt[tid] = pack2(lo, hi);
}

// ---------------------------------------------------------------------------
// xprep: xt[b][y+8][col+8][c] bf16 (interior). grid (128 y, 4 b), block 256.
// ---------------------------------------------------------------------------
__global__ __launch_bounds__(256) void k_xprep(
    const float* __restrict__ x, unsigned* __restrict__ xt)
{
    int y = blockIdx.x, b = blockIdx.y;
    int t = threadIdx.x;
    __shared__ float xsm[64*131];
    for (int ci0 = 0; ci0 < 128; ci0 += 64){
        for (int i=0;i<32;i++){
            int idx = t + 256*i;                 // 8192 = 64*128
            int col = idx & 127, ci = idx >> 7;
            xsm[ci*131 + col] = x[(((size_t)b*CIN + ci0+ci)*H + y)*W + col];
        }
        __syncthreads();
        for (int i=0;i<16;i++){
            int idx = t + 256*i;                 // 4096 = 128*32
            int cp = idx & 31, col = idx >> 5;
            unsigned u = pack2(xsm[(2*cp)*131 + col], xsm[(2*cp+1)*131 + col]);
            xt[(((size_t)b*XTD + y+8)*XTD + col+8)*64 + (ci0>>1) + cp] = u;
        }
        __syncthreads();
    }
}

// ---------------------------------------------------------------------------
// K1: dilated 3x3 conv via bf16 MFMA implicit GEMM. grid (64 hp, 16 zb),
// block 256 (4 waves). M=256 (2 rows), N=64, K=1152, c-chunk 16.
// Wave w: m-tiles {2w,2w+1}, n-tiles {0,1}; mfma_f32_32x32x16_bf16.
// ---------------------------------------------------------------------------
__global__ __launch_bounds__(256,2) void k_branch_mfma(
    const unsigned* __restrict__ xt, const unsigned* __restrict__ wbt,
    const float* __restrict__ b1, const float* __restrict__ b2,
    const float* __restrict__ b3, const float* __restrict__ b4,
    bf16* __restrict__ feats)
{
    int hp = blockIdx.x, zb = blockIdx.y;
    int d = zb >> 2, b = zb & 3;
    int dil = 2*d + 1;
    int h0 = hp*2;
    const float* bs = (d==0)?b1:(d==1)?b2:(d==2)?b3:b4;
    const float scale = (float)dil;

    __shared__ unsigned smem[10368 + 6912];      // As + Bs = 69.1 KB
    unsigned* As = smem;                          // [(row6*144+s)*12 + cpair]
    unsigned* Bs = smem + 10368;                  // [(tap*64+oc)*12 + cpair]
    const unsigned short* As16 = (const unsigned short*)As;
    const unsigned short* Bs16 = (const unsigned short*)Bs;

    int t = threadIdx.x;
    int lane = t & 63;
    int w = t >> 6;
    int l31 = lane & 31;
    int half = lane >> 5;

    bf16* fb = feats + (size_t)zb*COUT*HPWP;
    // border zeroing: x_pad borders for this block's two rows
    {
        int idx = t;                              // exactly 256 = 64oc*2row*2side
        int oc = idx >> 2, rr = (idx>>1)&1, side = idx&1;
        fb[(size_t)oc*HPWP + (h0+1+rr)*HPX + 3 + side*129] = f2b(0.f);
    }
    if (hp == 0){
        for (int idx=t; idx<2*COUT*HPX; idx+=256){
            int col = idx % HPX;
            int rocc = idx / HPX;
            int oc = rocc >> 1, side = rocc & 1;
            fb[(size_t)oc*HPWP + side*129*HPX + col] = f2b(0.f);
        }
    }

    f32x16 acc[2][2];
    #pragma unroll
    for (int i=0;i<2;i++)
      #pragma unroll
      for (int j=0;j<2;j++)
        #pragma unroll
        for (int e=0;e<16;e++) acc[i][j][e] = 0.f;

    const int width = 128 + 2*dil;
    const unsigned* xtb = xt + (size_t)b*XTD*XTD*64;
    int r = w >> 1;                               // waves 0,1 -> row0; 2,3 -> row1
    int pxb = (w & 1) * 64;

    for (int cg=0; cg<8; cg++){
        #pragma unroll
        for (int i=0;i<27;i++){
            int idx = t + 256*i;                  // 6912 = 6*144*8
            int cpair = idx & 7;
            int s = (idx >> 3) % 144;
            int row6 = idx / 1152;
            if (s < width){
                int ky = row6 >> 1, rr = row6 & 1;
                int yy = h0 + rr + (ky-1)*dil + 8;
                int cc = s - dil + 8;
                As[(row6*144 + s)*12 + cpair] = xtb[((size_t)yy*XTD + cc)*64 + cg*8 + cpair];
            }
        }
        #pragma unroll
        for (int i=0;i<18;i++){
            int idx = t + 256*i;                  // 4608 = 9*64*8
            int cpair = idx & 7;
            int oc = (idx >> 3) & 63;
            int tap = idx >> 9;
            Bs[(tap*64 + oc)*12 + cpair] = wbt[(((size_t)(d*9+tap))*64 + oc)*64 + cg*8 + cpair];
        }
        __syncthreads();
        #pragma unroll
        for (int tap=0; tap<9; tap++){
            int ky = tap/3, kx = tap%3;
            int rowb = (ky*2 + r)*144;
            s16x8 a0 = *(const s16x8*)(As16 + (rowb + pxb      + l31 + kx*dil)*24 + half*8);
            s16x8 a1 = *(const s16x8*)(As16 + (rowb + pxb + 32 + l31 + kx*dil)*24 + half*8);
            s16x8 bb0 = *(const s16x8*)(Bs16 + (tap*64      + l31)*24 + half*8);
            s16x8 bb1 = *(const s16x8*)(Bs16 + (tap*64 + 32 + l31)*24 + half*8);
            acc[0][0] = __builtin_amdgcn_mfma_f32_32x32x16_bf16(a0, bb0, acc[0][0], 0,0,0);
            acc[0][1] = __builtin_amdgcn_mfma_f32_32x32x16_bf16(a0, bb1, acc[0][1], 0,0,0);
            acc[1][0] = __builtin_amdgcn_mfma_f32_32x32x16_bf16(a1, bb0, acc[1][0], 0,0,0);
            acc[1][1] = __builtin_amdgcn_mfma_f32_32x32x16_bf16(a1, bb1, acc[1][1], 0,0,0);
        }
        __syncthreads();
    }

    // epilogue: bias+scale, transpose through LDS, coalesced global stores
    unsigned short* ep = (unsigned short*)smem;   // [oc 64][264]
    float bias0 = bs[l31], bias1 = bs[32 + l31];
    #pragma unroll
    for (int i=0;i<2;i++){
      #pragma unroll
      for (int j=0;j<2;j++){
        int oc = j*32 + l31;
        float bj = j ? bias1 : bias0;
        #pragma unroll
        for (int rg=0; rg<4; rg++){
            int m = 64*w + 32*i + 8*rg + 4*half;
            float v0 = (acc[i][j][4*rg+0] + bj)*scale;
            float v1 = (acc[i][j][4*rg+1] + bj)*scale;
            float v2 = (acc[i][j][4*rg+2] + bj)*scale;
            float v3 = (acc[i][j][4*rg+3] + bj)*scale;
            uint2 u; u.x = pack2(v0,v1); u.y = pack2(v2,v3);
            *(uint2*)(ep + oc*264 + m) = u;
        }
      }
    }
    __syncthreads();
    {
        int oc = t >> 2, q = t & 3;
        int r2 = q >> 1, colb = (q & 1)*64;
        unsigned short* dst = (unsigned short*)(fb + (size_t)oc*HPWP + (h0+1+r2)*HPX + 4 + colb);
        #pragma unroll
        for (int i=0;i<8;i++){
            uint4 v = *(const uint4*)(ep + oc*264 + q*64 + i*8);
            uint2 lo; lo.x = v.x; lo.y = v.y;
            uint2 hi; hi.x = v.z; hi.y = v.w;
            *(uint2*)(dst + i*8)     = lo;
            *(uint2*)(dst + i*8 + 4) = hi;
        }
    }
}

// ---------------------------------------------------------------------------
// K2: 3x3 conv pad=1, 64 -> 18 (offsets). grid (128 h, 16 zb), block 256.
// ---------------------------------------------------------------------------
__global__ __launch_bounds__(256,4) void k_offset_conv(
    const bf16* __restrict__ feats,
    const float* __restrict__ pw, const float* __restrict__ pb,
    bf16* __restrict__ offs)
{
    int h  = blockIdx.x;
    int zb = blockIdx.y;
    __shared__ float xs[8*3*132];
    __shared__ float ws2[8*9*24];
    int t = threadIdx.x;
    int w = t & 127;
    int half = t >> 7;
    float acc[9];
    #pragma unroll
    for (int j=0;j<9;j++) acc[j]=0.f;
    const bf16* fin = feats + (size_t)zb*COUT*HPWP;
    for (int c0=0; c0<COUT; c0+=8){
        for (int idx=t; idx<3120; idx+=256){
            int c = idx/390, r = idx%390, ky = r/130, col = r%130;
            xs[(c*3+ky)*132 + col] = b2f(fin[((size_t)(c0+c))*HPWP + (h+ky)*HPX + col + 3]);
        }
        for (int idx=t; idx<1296; idx+=256){
            int c = idx/162, r = idx%162, tap = r/18, o = r%18;
            ws2[(c*9+tap)*24 + (o/9)*12 + (o%9)] = pw[((size_t)o*COUT + c0+c)*9 + tap];
        }
        __syncthreads();
        #pragma unroll
        for (int c=0;c<8;c++)
          #pragma unroll
          for (int ky=0;ky<3;ky++)
            #pragma unroll
            for (int kx=0;kx<3;kx++){
               float xv = xs[(c*3+ky)*132 + w + kx];
               const float* wbase = &ws2[(c*9+ky*3+kx)*24 + half*12];
               float4 wa = *(const float4*)wbase;
               float4 wb = *(const float4*)(wbase+4);
               float w8 = wbase[8];
               acc[0]+=wa.x*xv; acc[1]+=wa.y*xv; acc[2]+=wa.z*xv; acc[3]+=wa.w*xv;
               acc[4]+=wb.x*xv; acc[5]+=wb.y*xv; acc[6]+=wb.z*xv; acc[7]+=wb.w*xv;
               acc[8]+=w8*xv;
            }
        __syncthreads();
    }
    #pragma unroll
    for (int j=0;j<9;j++){
        int oc = half*9+j;
        offs[((size_t)zb*18 + oc)*HW + h*W + w] = f2b(acc[j] + pb[oc]);
    }
}

// ---------------------------------------------------------------------------
// K3a: deformable sampling + dw einsum (K=576) + db for ONE branch.
// grid (128 h, 16 zb), block 256.
// ---------------------------------------------------------------------------
__global__ __launch_bounds__(256,4) void k_deform(
    const bf16* __restrict__ feats,
    const bf16* __restrict__ offs,
    const float* __restrict__ dw, const float* __restrict__ db,
    bf16* __restrict__ dout)
{
    int h  = blockIdx.x;
    int zb = blockIdx.y;
    int t  = threadIdx.x;
    int p0 = t & 31;
    int g  = t >> 5;

    __shared__ unsigned lidx[1152];
    __shared__ float coef[1152*4];
    __shared__ float sam[2*9*128];
    __shared__ float dwch[18*64];

    const bf16* obase = offs + (size_t)zb*18*HW + h*W;
    for (int idx=t; idx<1152; idx+=256){
        int p = idx & 127, n = idx >> 7;
        float offy = b2f(obase[n*HW + p]);
        float offx = b2f(obase[(n+9)*HW + p]);
        float py = (float)(h + n/3) + offy;
        float px = (float)(p + n%3) + offx;
        float fy = floorf(py), fx = floorf(px);
        float lty = fminf(fmaxf(fy,     0.f),129.f);
        float ltx = fminf(fmaxf(fx,     0.f),129.f);
        float rby = fminf(fmaxf(fy+1.f, 0.f),129.f);
        float rbx = fminf(fmaxf(fx+1.f, 0.f),129.f);
        float pyc = fminf(fmaxf(py,     0.f),129.f);
        float pxc = fminf(fmaxf(px,     0.f),129.f);
        float ay = 1.f + (lty-pyc), by = 1.f - (rby-pyc);
        float ax = 1.f + (ltx-pxc), bx = 1.f - (rbx-pxc);
        int ilty=(int)lty, iltx=(int)ltx;
        int dx = (int)rbx - iltx, dy = (int)rby - ilty;
        lidx[idx] = (unsigned)(ilty*HPX + iltx + 3) | ((unsigned)dx<<17) | ((unsigned)dy<<18);
        coef[idx*4+0] = ay*ax;
        coef[idx*4+1] = ay*bx;
        coef[idx*4+2] = by*ax;
        coef[idx*4+3] = by*bx;
    }
    float acc[4][8];
    #pragma unroll
    for (int k=0;k<4;k++)
      #pragma unroll
      for (int o=0;o<8;o++) acc[k][o]=0.f;
    __syncthreads();

    const bf16* fbase = feats + (size_t)zb*COUT*HPWP;
    for (int c0=0; c0<COUT; c0+=2){
        for (int idx=t; idx<1152; idx+=256){
            int o = idx & 63, rr = idx >> 6;
            dwch[rr*64+o] = dw[((size_t)o*COUT + c0 + rr/9)*9 + (rr%9)];
        }
        #pragma unroll
        for (int i=0;i<9;i++){
            int idx = t + 256*i;
            int p = idx & 127, cn = idx >> 7;
            int c = cn/9, n = cn - 9*c;
            int np = n*128 + p;
            unsigned u = lidx[np];
            int base = u & 0x1FFFF;
            int dx   = (u>>17)&1;
            int dyo  = ((u>>18)&1) ? HPX : 0;
            const bf16* fc = fbase + (size_t)(c0+c)*HPWP;
            float vlt = b2f(fc[base]);
            float vlb = b2f(fc[base+dx]);
            float vrt = b2f(fc[base+dyo]);
            float vrb = b2f(fc[base+dyo+dx]);
            const float4 cf = *(const float4*)&coef[np*4];
            sam[cn*128+p] = cf.x*vlt + cf.y*vlb + cf.z*vrt + cf.w*vrb;
        }
        __syncthreads();
        #pragma unroll
        for (int cn=0;cn<18;cn++){
            float s0 = sam[cn*128+p0];
            float s1 = sam[cn*128+p0+32];
            float s2 = sam[cn*128+p0+64];
            float s3 = sam[cn*128+p0+96];
            const float4* wp = (const float4*)&dwch[cn*64 + g*8];
            float4 wa = wp[0], wb = wp[1];
            float wv[8] = {wa.x,wa.y,wa.z,wa.w,wb.x,wb.y,wb.z,wb.w};
            #pragma unroll
            for (int o=0;o<8;o++){
                acc[0][o]+=wv[o]*s0; acc[1][o]+=wv[o]*s1;
                acc[2][o]+=wv[o]*s2; acc[3][o]+=wv[o]*s3;
            }
        }
        __syncthreads();
    }
    #pragma unroll
    for (int o=0;o<8;o++){
        int oc = g*8+o;
        float bias = db[oc];
        bf16* dst = dout + ((size_t)zb*COUT + oc)*HW + h*W;
        #pragma unroll
        for (int k=0;k<4;k++)
            dst[p0+32*k] = f2b(acc[k][o] + bias);
    }
}

// ---------------------------------------------------------------------------
// K3b: 1x1 conv 256 -> 64 + cb + ReLU. grid (128 h, 4 b, 2 s), block 256.
// ---------------------------------------------------------------------------
__global__ __launch_bounds__(256,4) void k_combine(
    const bf16* __restrict__ dout,
    const float* __restrict__ cw, const float* __restrict__ cb,
    float* __restrict__ out)
{
    int h = blockIdx.x;
    int b = blockIdx.y;
    int s = blockIdx.z;
    int t = threadIdx.x;
    int p0 = t & 63;
    int q  = t >> 6;
    __shared__ float cwl[64*32];
    float acc[2][8];
    #pragma unroll
    for (int k=0;k<2;k++)
      #pragma unroll
      for (int o=0;o<8;o++) acc[k][o]=0.f;

    for (int d=0; d<4; d++){
        for (int idx=t; idx<2048; idx+=256){
            int o32 = idx & 31, j = idx >> 5;
            cwl[j*32+o32] = cw[((size_t)(s*32+o32))*256 + d*64 + j];
        }
        __syncthreads();
        const bf16* dbase = dout + (size_t)((d*4+b)*COUT)*HW + h*W;
        #pragma unroll 8
        for (int jj=0; jj<64; jj++){
            float v0 = b2f(dbase[jj*HW + p0]);
            float v1 = b2f(dbase[jj*HW + p0+64]);
            const float4* wp = (const float4*)&cwl[jj*32 + q*8];
            float4 wa = wp[0], wb = wp[1];
            float wv[8] = {wa.x,wa.y,wa.z,wa.w,wb.x,wb.y,wb.z,wb.w};
            #pragma unroll
            for (int o=0;o<8;o++){
                acc[0][o]+=wv[o]*v0;
                acc[1][o]+=wv[o]*v1;
            }
        }
        __syncthreads();
    }
    #pragma unroll
    for (int o=0;o<8;o++){
        int oc = s*32 + q*8 + o;
        float bias = cb[oc];
        size_t base = (((size_t)b*COUT + oc)*H + h)*W;
        out[base + p0]      = fmaxf(acc[0][o]+bias, 0.f);
        out[base + p0 + 64] = fmaxf(acc[1][o]+bias, 0.f);
    }
}

extern "C" void kernel_launch(void* const* d_in, const int* in_sizes, int n_in,
                              void* d_out, int out_size, void* d_ws, size_t ws_size,
                              hipStream_t stream) {
    const float* x  = (const float*)d_in[0];
    const float* w1 = (const float*)d_in[1];
    const float* b1 = (const float*)d_in[2];
    const float* w2 = (const float*)d_in[3];
    const float* b2 = (const float*)d_in[4];
    const float* w3 = (const float*)d_in[5];
    const float* b3 = (const float*)d_in[6];
    const float* w4 = (const float*)d_in[7];
    const float* b4 = (const float*)d_in[8];
    const float* pw = (const float*)d_in[9];
    const float* pb = (const float*)d_in[10];
    const float* dw = (const float*)d_in[11];
    const float* db = (const float*)d_in[12];
    const float* cw = (const float*)d_in[13];
    const float* cb = (const float*)d_in[14];
    float* out = (float*)d_out;

    bf16* feats = (bf16*)d_ws;                              // 16*64*17680 el = 36.2 MB
    bf16* offs  = feats + (size_t)16*COUT*HPWP;             // 16*18*16384  =  9.4 MB
    bf16* region2 = offs + (size_t)16*18*HW;
    bf16* doutb = region2;                                  // 16*64*16384  = 33.6 MB
    unsigned* xt  = (unsigned*)region2;                     // 4*144*144*64 u32 = 21.2 MB (dead before doutb written)
    unsigned* wbt = xt + (size_t)4*XTD*XTD*64;              // 147456 u32 = 0.59 MB

    k_zero       <<<dim3(1024),     256, 0, stream>>>((uint4*)xt, (int)((size_t)4*XTD*XTD*64/4));
    k_wprep      <<<dim3(576),      256, 0, stream>>>(w1, w2, w3, w4, wbt);
    k_xprep      <<<dim3(128,4),    256, 0, stream>>>(x, xt);
    k_branch_mfma<<<dim3(64,16),    256, 0, stream>>>(xt, wbt, b1, b2, b3, b4, feats);
    k_offset_conv<<<dim3(128,16),   256, 0, stream>>>(feats, pw, pb, offs);
    k_deform     <<<dim3(128,16),   256, 0, stream>>>(feats, offs, dw, db, doutb);
    k_combine    <<<dim3(128,4,2),  256, 0, stream>>>(doutb, cw, cb, out);
}

// Round 4
// 913.879 us; speedup vs baseline: 3.3923x; 1.2215x over previous
//
#include <hip/hip_runtime.h>
#include <hip/hip_bf16.h>

#define H 128
#define W 128
#define CIN 128
#define COUT 64
#define HW (H*W)
// padded feats layout: [oc][y_pad 0..129][x: x_pad+3], row stride 136
#define HPX 136
#define HPWP (130*136)
// xt layout: [b][y+8 (144)][col+8 (144)][c 128] bf16
#define XTD 144

typedef __hip_bfloat16 bf16;
typedef __attribute__((ext_vector_type(8)))  short s16x8;
typedef __attribute__((ext_vector_type(16))) float f32x16;

__device__ __forceinline__ float b2f(bf16 v){ return __bfloat162float(v); }
__device__ __forceinline__ bf16  f2b(float v){ return __float2bfloat16(v); }
__device__ __forceinline__ unsigned pack2(float a, float b){
    unsigned short ua = __builtin_bit_cast(unsigned short, f2b(a));
    unsigned short ub = __builtin_bit_cast(unsigned short, f2b(b));
    return (unsigned)ua | ((unsigned)ub << 16);
}

// ---------------------------------------------------------------------------
// zero xt (21.2 MB) so xprep only fills the interior
// ---------------------------------------------------------------------------
__global__ __launch_bounds__(256) void k_zero(uint4* __restrict__ p, int n4){
    int stride = gridDim.x * 256;
    for (int i = blockIdx.x*256 + threadIdx.x; i < n4; i += stride)
        p[i] = make_uint4(0,0,0,0);
}

// ---------------------------------------------------------------------------
// wprep: wbt[d][tap][oc][c] bf16 from w_d[oc][c][tap] fp32. grid 576, block 256.
// ---------------------------------------------------------------------------
__global__ __launch_bounds__(256) void k_wprep(
    const float* __restrict__ w1, const float* __restrict__ w2,
    const float* __restrict__ w3, const float* __restrict__ w4,
    unsigned* __restrict__ wbt)
{
    int tid = blockIdx.x*256 + threadIdx.x;     // 147456 = 36*64*64
    int cpair = tid & 63;
    int oc    = (tid >> 6) & 63;
    int tapd  = tid >> 12;                       // 0..35
    int tap = tapd % 9, d = tapd / 9;
    const float* wt = (d==0)?w1:(d==1)?w2:(d==2)?w3:w4;
    float lo = wt[((size_t)oc*CIN + 2*cpair    )*9 + tap];
    float hi = wt[((size_t)oc*CIN + 2*cpair + 1)*9 + tap];
    wbt[tid] = pack2(lo, hi);
}

// ---------------------------------------------------------------------------
// dwprep: dwb[oc][n*64+c] bf16 (u32 pairs) from dw[oc][c][n] fp32. 72 blocks.
// ---------------------------------------------------------------------------
__global__ __launch_bounds__(256) void k_dwprep(
    const float* __restrict__ dw, unsigned* __restrict__ dwb)
{
    int i = blockIdx.x*256 + threadIdx.x;        // 18432 = 64*288
    if (i >= 64*288) return;
    int oc = i / 288;
    int r  = i % 288;                             // n*32 + cp
    int n = r >> 5, cp = r & 31;
    float lo = dw[((size_t)oc*64 + 2*cp    )*9 + n];
    float hi = dw[((size_t)oc*64 + 2*cp + 1)*9 + n];
    dwb[i] = pack2(lo, hi);
}

// ---------------------------------------------------------------------------
// xprep: xt[b][y+8][col+8][c] bf16 (interior). grid (128 y, 4 b), block 256.
// ---------------------------------------------------------------------------
__global__ __launch_bounds__(256) void k_xprep(
    const float* __restrict__ x, unsigned* __restrict__ xt)
{
    int y = blockIdx.x, b = blockIdx.y;
    int t = threadIdx.x;
    __shared__ float xsm[64*131];
    for (int ci0 = 0; ci0 < 128; ci0 += 64){
        for (int i=0;i<32;i++){
            int idx = t + 256*i;                 // 8192 = 64*128
            int col = idx & 127, ci = idx >> 7;
            xsm[ci*131 + col] = x[(((size_t)b*CIN + ci0+ci)*H + y)*W + col];
        }
        __syncthreads();
        for (int i=0;i<16;i++){
            int idx = t + 256*i;                 // 4096 = 128*32
            int cp = idx & 31, col = idx >> 5;
            unsigned u = pack2(xsm[(2*cp)*131 + col], xsm[(2*cp+1)*131 + col]);
            xt[(((size_t)b*XTD + y+8)*XTD + col+8)*64 + (ci0>>1) + cp] = u;
        }
        __syncthreads();
    }
}

// ---------------------------------------------------------------------------
// K1: dilated 3x3 conv via bf16 MFMA implicit GEMM. grid (64 hp, 16 zb),
// block 256 (4 waves). M=256 (2 rows), N=64, K=1152, c-chunk 16.
// ---------------------------------------------------------------------------
__global__ __launch_bounds__(256,2) void k_branch_mfma(
    const unsigned* __restrict__ xt, const unsigned* __restrict__ wbt,
    const float* __restrict__ b1, const float* __restrict__ b2,
    const float* __restrict__ b3, const float* __restrict__ b4,
    bf16* __restrict__ feats)
{
    int hp = blockIdx.x, zb = blockIdx.y;
    int d = zb >> 2, b = zb & 3;
    int dil = 2*d + 1;
    int h0 = hp*2;
    const float* bs = (d==0)?b1:(d==1)?b2:(d==2)?b3:b4;
    const float scale = (float)dil;

    __shared__ unsigned smem[10368 + 6912];      // As + Bs = 69.1 KB
    unsigned* As = smem;                          // [(row6*144+s)*12 + cpair]
    unsigned* Bs = smem + 10368;                  // [(tap*64+oc)*12 + cpair]
    const unsigned short* As16 = (const unsigned short*)As;
    const unsigned short* Bs16 = (const unsigned short*)Bs;

    int t = threadIdx.x;
    int lane = t & 63;
    int w = t >> 6;
    int l31 = lane & 31;
    int half = lane >> 5;

    bf16* fb = feats + (size_t)zb*COUT*HPWP;
    {
        int idx = t;                              // 256 = 64oc*2row*2side
        int oc = idx >> 2, rr = (idx>>1)&1, side = idx&1;
        fb[(size_t)oc*HPWP + (h0+1+rr)*HPX + 3 + side*129] = f2b(0.f);
    }
    if (hp == 0){
        for (int idx=t; idx<2*COUT*HPX; idx+=256){
            int col = idx % HPX;
            int rocc = idx / HPX;
            int oc = rocc >> 1, side = rocc & 1;
            fb[(size_t)oc*HPWP + side*129*HPX + col] = f2b(0.f);
        }
    }

    f32x16 acc[2][2];
    #pragma unroll
    for (int i=0;i<2;i++)
      #pragma unroll
      for (int j=0;j<2;j++)
        #pragma unroll
        for (int e=0;e<16;e++) acc[i][j][e] = 0.f;

    const int width = 128 + 2*dil;
    const unsigned* xtb = xt + (size_t)b*XTD*XTD*64;
    int r = w >> 1;
    int pxb = (w & 1) * 64;

    for (int cg=0; cg<8; cg++){
        #pragma unroll
        for (int i=0;i<27;i++){
            int idx = t + 256*i;                  // 6912 = 6*144*8
            int cpair = idx & 7;
            int s = (idx >> 3) % 144;
            int row6 = idx / 1152;
            if (s < width){
                int ky = row6 >> 1, rr = row6 & 1;
                int yy = h0 + rr + (ky-1)*dil + 8;
                int cc = s - dil + 8;
                As[(row6*144 + s)*12 + cpair] = xtb[((size_t)yy*XTD + cc)*64 + cg*8 + cpair];
            }
        }
        #pragma unroll
        for (int i=0;i<18;i++){
            int idx = t + 256*i;                  // 4608 = 9*64*8
            int cpair = idx & 7;
            int oc = (idx >> 3) & 63;
            int tap = idx >> 9;
            Bs[(tap*64 + oc)*12 + cpair] = wbt[(((size_t)(d*9+tap))*64 + oc)*64 + cg*8 + cpair];
        }
        __syncthreads();
        #pragma unroll
        for (int tap=0; tap<9; tap++){
            int ky = tap/3, kx = tap%3;
            int rowb = (ky*2 + r)*144;
            s16x8 a0 = *(const s16x8*)(As16 + (rowb + pxb      + l31 + kx*dil)*24 + half*8);
            s16x8 a1 = *(const s16x8*)(As16 + (rowb + pxb + 32 + l31 + kx*dil)*24 + half*8);
            s16x8 bb0 = *(const s16x8*)(Bs16 + (tap*64      + l31)*24 + half*8);
            s16x8 bb1 = *(const s16x8*)(Bs16 + (tap*64 + 32 + l31)*24 + half*8);
            acc[0][0] = __builtin_amdgcn_mfma_f32_32x32x16_bf16(a0, bb0, acc[0][0], 0,0,0);
            acc[0][1] = __builtin_amdgcn_mfma_f32_32x32x16_bf16(a0, bb1, acc[0][1], 0,0,0);
            acc[1][0] = __builtin_amdgcn_mfma_f32_32x32x16_bf16(a1, bb0, acc[1][0], 0,0,0);
            acc[1][1] = __builtin_amdgcn_mfma_f32_32x32x16_bf16(a1, bb1, acc[1][1], 0,0,0);
        }
        __syncthreads();
    }

    unsigned short* ep = (unsigned short*)smem;   // [oc 64][264]
    float bias0 = bs[l31], bias1 = bs[32 + l31];
    #pragma unroll
    for (int i=0;i<2;i++){
      #pragma unroll
      for (int j=0;j<2;j++){
        int oc = j*32 + l31;
        float bj = j ? bias1 : bias0;
        #pragma unroll
        for (int rg=0; rg<4; rg++){
            int m = 64*w + 32*i + 8*rg + 4*half;
            float v0 = (acc[i][j][4*rg+0] + bj)*scale;
            float v1 = (acc[i][j][4*rg+1] + bj)*scale;
            float v2 = (acc[i][j][4*rg+2] + bj)*scale;
            float v3 = (acc[i][j][4*rg+3] + bj)*scale;
            uint2 u; u.x = pack2(v0,v1); u.y = pack2(v2,v3);
            *(uint2*)(ep + oc*264 + m) = u;
        }
      }
    }
    __syncthreads();
    {
        int oc = t >> 2, q = t & 3;
        int r2 = q >> 1, colb = (q & 1)*64;
        unsigned short* dst = (unsigned short*)(fb + (size_t)oc*HPWP + (h0+1+r2)*HPX + 4 + colb);
        #pragma unroll
        for (int i=0;i<8;i++){
            uint4 v = *(const uint4*)(ep + oc*264 + q*64 + i*8);
            uint2 lo; lo.x = v.x; lo.y = v.y;
            uint2 hi; hi.x = v.z; hi.y = v.w;
            *(uint2*)(dst + i*8)     = lo;
            *(uint2*)(dst + i*8 + 4) = hi;
        }
    }
}

// ---------------------------------------------------------------------------
// K2: 3x3 conv pad=1, 64 -> 18 (offsets). grid (128 h, 16 zb), block 256.
// ---------------------------------------------------------------------------
__global__ __launch_bounds__(256,4) void k_offset_conv(
    const bf16* __restrict__ feats,
    const float* __restrict__ pw, const float* __restrict__ pb,
    bf16* __restrict__ offs)
{
    int h  = blockIdx.x;
    int zb = blockIdx.y;
    __shared__ float xs[8*3*132];
    __shared__ float ws2[8*9*24];
    int t = threadIdx.x;
    int w = t & 127;
    int half = t >> 7;
    float acc[9];
    #pragma unroll
    for (int j=0;j<9;j++) acc[j]=0.f;
    const bf16* fin = feats + (size_t)zb*COUT*HPWP;
    for (int c0=0; c0<COUT; c0+=8){
        for (int idx=t; idx<3120; idx+=256){
            int c = idx/390, r = idx%390, ky = r/130, col = r%130;
            xs[(c*3+ky)*132 + col] = b2f(fin[((size_t)(c0+c))*HPWP + (h+ky)*HPX + col + 3]);
        }
        for (int idx=t; idx<1296; idx+=256){
            int c = idx/162, r = idx%162, tap = r/18, o = r%18;
            ws2[(c*9+tap)*24 + (o/9)*12 + (o%9)] = pw[((size_t)o*COUT + c0+c)*9 + tap];
        }
        __syncthreads();
        #pragma unroll
        for (int c=0;c<8;c++)
          #pragma unroll
          for (int ky=0;ky<3;ky++)
            #pragma unroll
            for (int kx=0;kx<3;kx++){
               float xv = xs[(c*3+ky)*132 + w + kx];
               const float* wbase = &ws2[(c*9+ky*3+kx)*24 + half*12];
               float4 wa = *(const float4*)wbase;
               float4 wb = *(const float4*)(wbase+4);
               float w8 = wbase[8];
               acc[0]+=wa.x*xv; acc[1]+=wa.y*xv; acc[2]+=wa.z*xv; acc[3]+=wa.w*xv;
               acc[4]+=wb.x*xv; acc[5]+=wb.y*xv; acc[6]+=wb.z*xv; acc[7]+=wb.w*xv;
               acc[8]+=w8*xv;
            }
        __syncthreads();
    }
    #pragma unroll
    for (int j=0;j<9;j++){
        int oc = half*9+j;
        offs[((size_t)zb*18 + oc)*HW + h*W + w] = f2b(acc[j] + pb[oc]);
    }
}

// ---------------------------------------------------------------------------
// K3a: deformable sampling + dw einsum via bf16 MFMA. grid (128 h, 16 zb),
// block 256 (4 waves). M=128 px, N=64 oc, K=576 (n-major: 9 n x 4 sub x 16 c).
// thread: px=t&127, kh=t>>7. Coords in registers (once per n). Wave w owns
// m-tile w (32 px), both n-tiles. 2 mfma_f32_32x32x16_bf16 per sub-chunk.
// ---------------------------------------------------------------------------
__global__ __launch_bounds__(256,3) void k_deform_mfma(
    const bf16* __restrict__ feats,
    const bf16* __restrict__ offs,
    const unsigned* __restrict__ dwb,   // [oc][288] u32 = bf16[oc][n*64+c]
    const float* __restrict__ db,
    bf16* __restrict__ dout)
{
    int h  = blockIdx.x;
    int zb = blockIdx.y;
    int t  = threadIdx.x;
    int px = t & 127;
    int kh = t >> 7;
    int lane = t & 63;
    int w = t >> 6;
    int l31 = lane & 31;
    int half = lane >> 5;

    __shared__ unsigned smem_u32[4352];           // 17408 B
    unsigned* Asu = smem_u32;                     // 1024 u32: [kh*128+m][4]
    unsigned* Bsu = smem_u32 + 1024;              // 512  u32: [kh*64+oc][4]
    const unsigned short* As16 = (const unsigned short*)Asu;
    const unsigned short* Bs16 = (const unsigned short*)Bsu;

    const bf16* obase = offs + (size_t)zb*18*HW + h*W;
    const bf16* fbase = feats + (size_t)zb*COUT*HPWP;

    f32x16 acc0, acc1;
    #pragma unroll
    for (int e=0;e<16;e++){ acc0[e]=0.f; acc1[e]=0.f; }

    int oc_s = (t>>2) & 63;
    int jp_s = t & 3;
    const unsigned* dwrow = dwb + (size_t)oc_s*288 + jp_s;

    for (int n=0; n<9; n++){
        float offy = b2f(obase[n*HW + px]);
        float offx = b2f(obase[(n+9)*HW + px]);
        float py = (float)(h + n/3) + offy;
        float pxf = (float)(px + n%3) + offx;
        float fy = floorf(py), fx = floorf(pxf);
        float lty = fminf(fmaxf(fy,     0.f),129.f);
        float ltx = fminf(fmaxf(fx,     0.f),129.f);
        float rby = fminf(fmaxf(fy+1.f, 0.f),129.f);
        float rbx = fminf(fmaxf(fx+1.f, 0.f),129.f);
        float pyc = fminf(fmaxf(py,     0.f),129.f);
        float pxc = fminf(fmaxf(pxf,    0.f),129.f);
        float ay = 1.f + (lty-pyc), by = 1.f - (rby-pyc);
        float ax = 1.f + (ltx-pxc), bx = 1.f - (rbx-pxc);
        float glt = ay*ax, glb = ay*bx, grt = by*ax, grb = by*bx;
        int base = (int)lty*HPX + (int)ltx + 3;
        int dx   = (int)rbx - (int)ltx;              // 0/1
        int dyo  = ((int)rby - (int)lty) * HPX;      // 0/HPX

        for (int sub=0; sub<4; sub++){
            const bf16* fc = fbase + (size_t)(sub*16 + kh*8)*HPWP + base;
            unsigned pk[4];
            #pragma unroll
            for (int jp=0;jp<4;jp++){
                float sv[2];
                #pragma unroll
                for (int e=0;e<2;e++){
                    const bf16* f = fc + (size_t)(2*jp+e)*HPWP;
                    float vlt = b2f(f[0]);
                    float vlb = b2f(f[dx]);
                    float vrt = b2f(f[dyo]);
                    float vrb = b2f(f[dyo+dx]);
                    sv[e] = glt*vlt + glb*vlb + grt*vrt + grb*vrb;
                }
                pk[jp] = pack2(sv[0], sv[1]);
            }
            uint4 av; av.x=pk[0]; av.y=pk[1]; av.z=pk[2]; av.w=pk[3];
            *(uint4*)&Asu[(kh*128 + px)*4] = av;
            unsigned bsrc = n*32 + sub*8;
            Bsu[t]       = dwrow[bsrc];
            Bsu[t + 256] = dwrow[bsrc + 4];
            __syncthreads();
            s16x8 a  = *(const s16x8*)(As16 + ((half*128) + 32*w + l31)*8);
            s16x8 b0 = *(const s16x8*)(Bs16 + ((half*64)  + l31)*8);
            s16x8 b1 = *(const s16x8*)(Bs16 + ((half*64)  + 32 + l31)*8);
            acc0 = __builtin_amdgcn_mfma_f32_32x32x16_bf16(a, b0, acc0, 0,0,0);
            acc1 = __builtin_amdgcn_mfma_f32_32x32x16_bf16(a, b1, acc1, 0,0,0);
            __syncthreads();
        }
    }

    // epilogue: +db, transpose via LDS, coalesced uint4 stores
    unsigned short* ep = (unsigned short*)smem_u32;   // [64 oc][136]
    #pragma unroll
    for (int nt=0; nt<2; nt++){
        int oc = nt*32 + l31;
        float bias = db[oc];
        const f32x16& A = nt ? acc1 : acc0;
        #pragma unroll
        for (int g=0; g<4; g++){
            int m = 32*w + 4*half + 8*g;
            uint2 u;
            u.x = pack2(A[4*g+0]+bias, A[4*g+1]+bias);
            u.y = pack2(A[4*g+2]+bias, A[4*g+3]+bias);
            *(uint2*)(ep + oc*136 + m) = u;
        }
    }
    __syncthreads();
    bf16* dbase = dout + ((size_t)zb*COUT)*HW + h*W;
    #pragma unroll
    for (int it=0; it<4; it++){
        int i = t + 256*it;                  // 1024 = 64 oc * 16 seg
        int oc = i >> 4, seg = i & 15;
        *(uint4*)((unsigned short*)dbase + (size_t)oc*HW + seg*8) =
            *(const uint4*)(ep + oc*136 + seg*8);
    }
}

// ---------------------------------------------------------------------------
// K3b: 1x1 conv 256 -> 64 + cb + ReLU. grid (128 h, 4 b, 2 s), block 256.
// ---------------------------------------------------------------------------
__global__ __launch_bounds__(256,4) void k_combine(
    const bf16* __restrict__ dout,
    const float* __restrict__ cw, const float* __restrict__ cb,
    float* __restrict__ out)
{
    int h = blockIdx.x;
    int b = blockIdx.y;
    int s = blockIdx.z;
    int t = threadIdx.x;
    int p0 = t & 63;
    int q  = t >> 6;
    __shared__ float cwl[64*32];
    float acc[2][8];
    #pragma unroll
    for (int k=0;k<2;k++)
      #pragma unroll
      for (int o=0;o<8;o++) acc[k][o]=0.f;

    for (int d=0; d<4; d++){
        for (int idx=t; idx<2048; idx+=256){
            int o32 = idx & 31, j = idx >> 5;
            cwl[j*32+o32] = cw[((size_t)(s*32+o32))*256 + d*64 + j];
        }
        __syncthreads();
        const bf16* dbase = dout + (size_t)((d*4+b)*COUT)*HW + h*W;
        #pragma unroll 8
        for (int jj=0; jj<64; jj++){
            float v0 = b2f(dbase[jj*HW + p0]);
            float v1 = b2f(dbase[jj*HW + p0+64]);
            const float4* wp = (const float4*)&cwl[jj*32 + q*8];
            float4 wa = wp[0], wb = wp[1];
            float wv[8] = {wa.x,wa.y,wa.z,wa.w,wb.x,wb.y,wb.z,wb.w};
            #pragma unroll
            for (int o=0;o<8;o++){
                acc[0][o]+=wv[o]*v0;
                acc[1][o]+=wv[o]*v1;
            }
        }
        __syncthreads();
    }
    #pragma unroll
    for (int o=0;o<8;o++){
        int oc = s*32 + q*8 + o;
        float bias = cb[oc];
        size_t base = (((size_t)b*COUT + oc)*H + h)*W;
        out[base + p0]      = fmaxf(acc[0][o]+bias, 0.f);
        out[base + p0 + 64] = fmaxf(acc[1][o]+bias, 0.f);
    }
}

extern "C" void kernel_launch(void* const* d_in, const int* in_sizes, int n_in,
                              void* d_out, int out_size, void* d_ws, size_t ws_size,
                              hipStream_t stream) {
    const float* x  = (const float*)d_in[0];
    const float* w1 = (const float*)d_in[1];
    const float* b1 = (const float*)d_in[2];
    const float* w2 = (const float*)d_in[3];
    const float* b2 = (const float*)d_in[4];
    const float* w3 = (const float*)d_in[5];
    const float* b3 = (const float*)d_in[6];
    const float* w4 = (const float*)d_in[7];
    const float* b4 = (const float*)d_in[8];
    const float* pw = (const float*)d_in[9];
    const float* pb = (const float*)d_in[10];
    const float* dw = (const float*)d_in[11];
    const float* db = (const float*)d_in[12];
    const float* cw = (const float*)d_in[13];
    const float* cb = (const float*)d_in[14];
    float* out = (float*)d_out;

    bf16* feats = (bf16*)d_ws;                              // 16*64*17680 el = 36.2 MB
    bf16* offs  = feats + (size_t)16*COUT*HPWP;             // 16*18*16384  =  9.4 MB
    bf16* region2 = offs + (size_t)16*18*HW;
    bf16* doutb = region2;                                  // 16*64*16384  = 33.6 MB
    unsigned* xt  = (unsigned*)region2;                     // 21.2 MB (dead before doutb written)
    unsigned* wbt = xt + (size_t)4*XTD*XTD*64;              // 0.59 MB (dead before doutb written)
    unsigned* dwb = (unsigned*)(doutb + (size_t)16*COUT*HW);// 73.7 KB, AFTER doutb (live during k_deform)

    k_zero       <<<dim3(1024),     256, 0, stream>>>((uint4*)xt, (int)((size_t)4*XTD*XTD*64/4));
    k_wprep      <<<dim3(576),      256, 0, stream>>>(w1, w2, w3, w4, wbt);
    k_dwprep     <<<dim3(72),       256, 0, stream>>>(dw, dwb);
    k_xprep      <<<dim3(128,4),    256, 0, stream>>>(x, xt);
    k_branch_mfma<<<dim3(64,16),    256, 0, stream>>>(xt, wbt, b1, b2, b3, b4, feats);
    k_offset_conv<<<dim3(128,16),   256, 0, stream>>>(feats, pw, pb, offs);
    k_deform_mfma<<<dim3(128,16),   256, 0, stream>>>(feats, offs, dwb, db, doutb);
    k_combine    <<<dim3(128,4,2),  256, 0, stream>>>(doutb, cw, cb, out);
}

// Round 5
// 587.052 us; speedup vs baseline: 5.2809x; 1.5567x over previous
//
#include <hip/hip_runtime.h>
#include <hip/hip_bf16.h>

#define H 128
#define W 128
#define CIN 128
#define COUT 64
#define HW (H*W)
#define XW 130                    // padded spatial dim (y,x in [0,129])
#define FSL (XW*XW*64)            // feats2 elems per zb slice (NHWC bf16)
#define XTD 144                   // xt padded dim

typedef __hip_bfloat16 bf16;
typedef __attribute__((ext_vector_type(8)))  short s16x8;
typedef __attribute__((ext_vector_type(16))) float f32x16;

__device__ __forceinline__ float b2f(bf16 v){ return __bfloat162float(v); }
__device__ __forceinline__ bf16  f2b(float v){ return __float2bfloat16(v); }
__device__ __forceinline__ unsigned pack2(float a, float b){
    unsigned short ua = __builtin_bit_cast(unsigned short, f2b(a));
    unsigned short ub = __builtin_bit_cast(unsigned short, f2b(b));
    return (unsigned)ua | ((unsigned)ub << 16);
}
__device__ __forceinline__ unsigned short b16u(float v){
    return __builtin_bit_cast(unsigned short, f2b(v));
}
__device__ __forceinline__ float2 up2(unsigned u){
    float lo = __builtin_bit_cast(float, u << 16);
    float hi = __builtin_bit_cast(float, u & 0xFFFF0000u);
    return make_float2(lo, hi);
}

// ---------------------------------------------------------------------------
// k_prep: [0,1024) zero xt; [1024,1600) wbt; [1600,1672) dwb2; [1672,1704) cwb2
// ---------------------------------------------------------------------------
__global__ __launch_bounds__(256) void k_prep(
    const float* __restrict__ w1, const float* __restrict__ w2,
    const float* __restrict__ w3, const float* __restrict__ w4,
    const float* __restrict__ dw, const float* __restrict__ cw,
    uint4* __restrict__ xt4, unsigned* __restrict__ wbt,
    unsigned* __restrict__ dwb2, unsigned* __restrict__ cwb2)
{
    int bid = blockIdx.x;
    int t = threadIdx.x;
    if (bid < 1024){
        const int n4 = (4*XTD*XTD*64)/4;        // 1327104
        for (int i = bid*256 + t; i < n4; i += 1024*256)
            xt4[i] = make_uint4(0,0,0,0);
    } else if (bid < 1600){
        int tid = (bid-1024)*256 + t;            // 147456 = 36*64*64
        int cpair = tid & 63;
        int oc = (tid>>6)&63;
        int tapd = tid>>12;
        int tap = tapd%9, d = tapd/9;
        const float* wt = (d==0)?w1:(d==1)?w2:(d==2)?w3:w4;
        wbt[tid] = pack2(wt[((size_t)oc*CIN + 2*cpair  )*9 + tap],
                         wt[((size_t)oc*CIN + 2*cpair+1)*9 + tap]);
    } else if (bid < 1672){
        int i = (bid-1600)*256 + t;              // 18432: dwb2[n][oc][cp32]
        int n = i>>11, oc = (i>>5)&63, cp = i&31;
        dwb2[i] = pack2(dw[((size_t)oc*64 + 2*cp  )*9 + n],
                        dw[((size_t)oc*64 + 2*cp+1)*9 + n]);
    } else {
        int i = (bid-1672)*256 + t;              // 8192: cwb2[oc][cp128]
        int oc = i>>7, cp = i&127;
        cwb2[i] = pack2(cw[(size_t)oc*256 + 2*cp], cw[(size_t)oc*256 + 2*cp+1]);
    }
}

// ---------------------------------------------------------------------------
// xprep: xt[b][y+8][col+8][c] bf16 (interior). grid (128 y, 4 b), block 256.
// ---------------------------------------------------------------------------
__global__ __launch_bounds__(256) void k_xprep(
    const float* __restrict__ x, unsigned* __restrict__ xt)
{
    int y = blockIdx.x, b = blockIdx.y;
    int t = threadIdx.x;
    __shared__ float xsm[64*131];
    for (int ci0 = 0; ci0 < 128; ci0 += 64){
        for (int i=0;i<32;i++){
            int idx = t + 256*i;
            int col = idx & 127, ci = idx >> 7;
            xsm[ci*131 + col] = x[(((size_t)b*CIN + ci0+ci)*H + y)*W + col];
        }
        __syncthreads();
        for (int i=0;i<16;i++){
            int idx = t + 256*i;
            int cp = idx & 31, col = idx >> 5;
            unsigned u = pack2(xsm[(2*cp)*131 + col], xsm[(2*cp+1)*131 + col]);
            xt[(((size_t)b*XTD + y+8)*XTD + col+8)*64 + (ci0>>1) + cp] = u;
        }
        __syncthreads();
    }
}

// ---------------------------------------------------------------------------
// K1: dilated 3x3 conv via bf16 MFMA implicit GEMM. grid (64 hp, 16 zb),
// block 256. Writes feats2 NHWC [zb][y][x][c64] with zero borders.
// ---------------------------------------------------------------------------
__global__ __launch_bounds__(256,2) void k_branch_mfma(
    const unsigned* __restrict__ xt, const unsigned* __restrict__ wbt,
    const float* __restrict__ b1, const float* __restrict__ b2,
    const float* __restrict__ b3, const float* __restrict__ b4,
    bf16* __restrict__ feats2)
{
    int hp = blockIdx.x, zb = blockIdx.y;
    int d = zb >> 2, b = zb & 3;
    int dil = 2*d + 1;
    int h0 = hp*2;
    const float* bs = (d==0)?b1:(d==1)?b2:(d==2)?b3:b4;
    const float scale = (float)dil;

    __shared__ unsigned smem[10368 + 6912];
    unsigned* As = smem;
    unsigned* Bs = smem + 10368;
    const unsigned short* As16 = (const unsigned short*)As;
    const unsigned short* Bs16 = (const unsigned short*)Bs;

    int t = threadIdx.x;
    int lane = t & 63;
    int w = t >> 6;
    int l31 = lane & 31;
    int half = lane >> 5;

    bf16* fb = feats2 + (size_t)zb*FSL;
    // x-borders for this block's two rows (y = h0+1, h0+2), x in {0,129}
    if (t < 32){
        int yy = h0 + 1 + (t>>4);
        int side = (t>>3)&1;
        int q = t & 7;
        uint4 z = make_uint4(0,0,0,0);
        *(uint4*)((unsigned short*)fb + ((size_t)yy*XW + side*129)*64 + q*8) = z;
    }
    if (hp == 0){   // y=0 and y=129 rows, all x, all c
        uint4 z = make_uint4(0,0,0,0);
        for (int i=t; i<2080; i+=256){
            int row = i / 1040;
            int r = i % 1040;
            int xx = r >> 3, q = r & 7;
            *(uint4*)((unsigned short*)fb + ((size_t)(row*129)*XW + xx)*64 + q*8) = z;
        }
    }

    f32x16 acc[2][2];
    #pragma unroll
    for (int i=0;i<2;i++)
      #pragma unroll
      for (int j=0;j<2;j++)
        #pragma unroll
        for (int e=0;e<16;e++) acc[i][j][e] = 0.f;

    const int width = 128 + 2*dil;
    const unsigned* xtb = xt + (size_t)b*XTD*XTD*64;
    int r = w >> 1;
    int pxb = (w & 1) * 64;

    for (int cg=0; cg<8; cg++){
        #pragma unroll
        for (int i=0;i<27;i++){
            int idx = t + 256*i;
            int cpair = idx & 7;
            int s = (idx >> 3) % 144;
            int row6 = idx / 1152;
            if (s < width){
                int ky = row6 >> 1, rr = row6 & 1;
                int yy = h0 + rr + (ky-1)*dil + 8;
                int cc = s - dil + 8;
                As[(row6*144 + s)*12 + cpair] = xtb[((size_t)yy*XTD + cc)*64 + cg*8 + cpair];
            }
        }
        #pragma unroll
        for (int i=0;i<18;i++){
            int idx = t + 256*i;
            int cpair = idx & 7;
            int oc = (idx >> 3) & 63;
            int tap = idx >> 9;
            Bs[(tap*64 + oc)*12 + cpair] = wbt[(((size_t)(d*9+tap))*64 + oc)*64 + cg*8 + cpair];
        }
        __syncthreads();
        #pragma unroll
        for (int tap=0; tap<9; tap++){
            int ky = tap/3, kx = tap%3;
            int rowb = (ky*2 + r)*144;
            s16x8 a0 = *(const s16x8*)(As16 + (rowb + pxb      + l31 + kx*dil)*24 + half*8);
            s16x8 a1 = *(const s16x8*)(As16 + (rowb + pxb + 32 + l31 + kx*dil)*24 + half*8);
            s16x8 bb0 = *(const s16x8*)(Bs16 + (tap*64      + l31)*24 + half*8);
            s16x8 bb1 = *(const s16x8*)(Bs16 + (tap*64 + 32 + l31)*24 + half*8);
            acc[0][0] = __builtin_amdgcn_mfma_f32_32x32x16_bf16(a0, bb0, acc[0][0], 0,0,0);
            acc[0][1] = __builtin_amdgcn_mfma_f32_32x32x16_bf16(a0, bb1, acc[0][1], 0,0,0);
            acc[1][0] = __builtin_amdgcn_mfma_f32_32x32x16_bf16(a1, bb0, acc[1][0], 0,0,0);
            acc[1][1] = __builtin_amdgcn_mfma_f32_32x32x16_bf16(a1, bb1, acc[1][1], 0,0,0);
        }
        __syncthreads();
    }

    // epilogue: bias+scale, stage ep[m 256][oc 64] u16, NHWC vector stores
    unsigned short* ep = (unsigned short*)smem;
    float bias0 = bs[l31], bias1 = bs[32 + l31];
    #pragma unroll
    for (int i=0;i<2;i++){
      #pragma unroll
      for (int j=0;j<2;j++){
        int oc = j*32 + l31;
        float bj = j ? bias1 : bias0;
        #pragma unroll
        for (int rg=0; rg<4; rg++){
            int m0 = 64*w + 32*i + 8*rg + 4*half;
            #pragma unroll
            for (int e=0;e<4;e++)
                ep[(m0+e)*64 + oc] = b16u((acc[i][j][4*rg+e] + bj)*scale);
        }
      }
    }
    __syncthreads();
    {
        int row = t >> 7, pxm = t & 127;
        unsigned short* drow = (unsigned short*)fb + ((size_t)(h0+1+row)*XW + pxm + 1)*64;
        const unsigned short* srow = ep + t*64;
        #pragma unroll
        for (int q=0;q<8;q++)
            *(uint4*)(drow + q*8) = *(const uint4*)(srow + q*8);
    }
}

// ---------------------------------------------------------------------------
// K2: 3x3 conv pad=1, 64 -> 18 (offsets) from NHWC feats2.
// grid (128 h, 16 zb), block 256.
// ---------------------------------------------------------------------------
__global__ __launch_bounds__(256,4) void k_offset_conv(
    const bf16* __restrict__ feats2,
    const float* __restrict__ pw, const float* __restrict__ pb,
    bf16* __restrict__ offs)
{
    int h  = blockIdx.x;
    int zb = blockIdx.y;
    __shared__ float xs[8*3*132];
    __shared__ float ws2[8*9*24];
    int t = threadIdx.x;
    int w = t & 127;
    int half = t >> 7;
    float acc[9];
    #pragma unroll
    for (int j=0;j<9;j++) acc[j]=0.f;
    const unsigned short* fin = (const unsigned short*)(feats2 + (size_t)zb*FSL);
    for (int c0=0; c0<COUT; c0+=8){
        for (int idx=t; idx<390; idx+=256){
            int ky = idx/130, col = idx%130;
            unsigned u[4];
            *(uint4*)u = *(const uint4*)(fin + ((size_t)(h+ky)*XW + col)*64 + c0);
            #pragma unroll
            for (int k=0;k<4;k++){
                float2 f = up2(u[k]);
                xs[((2*k  )*3+ky)*132 + col] = f.x;
                xs[((2*k+1)*3+ky)*132 + col] = f.y;
            }
        }
        for (int idx=t; idx<1296; idx+=256){
            int c = idx/162, r = idx%162, tap = r/18, o = r%18;
            ws2[(c*9+tap)*24 + (o/9)*12 + (o%9)] = pw[((size_t)o*COUT + c0+c)*9 + tap];
        }
        __syncthreads();
        #pragma unroll
        for (int c=0;c<8;c++)
          #pragma unroll
          for (int ky=0;ky<3;ky++)
            #pragma unroll
            for (int kx=0;kx<3;kx++){
               float xv = xs[(c*3+ky)*132 + w + kx];
               const float* wbase = &ws2[(c*9+ky*3+kx)*24 + half*12];
               float4 wa = *(const float4*)wbase;
               float4 wb = *(const float4*)(wbase+4);
               float w8 = wbase[8];
               acc[0]+=wa.x*xv; acc[1]+=wa.y*xv; acc[2]+=wa.z*xv; acc[3]+=wa.w*xv;
               acc[4]+=wb.x*xv; acc[5]+=wb.y*xv; acc[6]+=wb.z*xv; acc[7]+=wb.w*xv;
               acc[8]+=w8*xv;
            }
        __syncthreads();
    }
    #pragma unroll
    for (int j=0;j<9;j++){
        int oc = half*9+j;
        offs[((size_t)zb*18 + oc)*HW + h*W + w] = f2b(acc[j] + pb[oc]);
    }
}

// ---------------------------------------------------------------------------
// K3a: deform sampling + dw einsum via bf16 MFMA, NHWC feats.
// grid 2048 1-D, XCD swizzle: zb = (bid&7) + 8*(bid>>10), h = (bid>>3)&127.
// thread: px=t&127, kh=t>>7 (channel half). Writes dout2 NHWC [zb][h][px][oc].
// ---------------------------------------------------------------------------
__global__ __launch_bounds__(256,4) void k_deform_mfma(
    const bf16* __restrict__ feats2,
    const bf16* __restrict__ offs,
    const unsigned* __restrict__ dwb2,  // [n][oc][cp32] u32
    const float* __restrict__ db,
    bf16* __restrict__ dout2)
{
    int bid = blockIdx.x;
    int xcd  = bid & 7;
    int h    = (bid >> 3) & 127;
    int pass = bid >> 10;
    int zb   = xcd + 8*pass;

    int t = threadIdx.x;
    int px = t & 127, kh = t >> 7;
    int lane = t & 63, w = t >> 6;
    int l31 = lane & 31, half = lane >> 5;

    __shared__ unsigned Asu[4096];   // [sub2half 8][px 128][4 u32] = 16 KB
    __shared__ unsigned Bsu[2304];   // [oc 64][36 pad] = 9 KB

    const bf16* obase = offs + (size_t)zb*18*HW + h*W;
    const unsigned short* fbase = (const unsigned short*)(feats2 + (size_t)zb*FSL);

    f32x16 acc0, acc1;
    #pragma unroll
    for (int e=0;e<16;e++){ acc0[e]=0.f; acc1[e]=0.f; }

    for (int n=0; n<9; n++){
        float offy = b2f(obase[n*HW + px]);
        float offx = b2f(obase[(n+9)*HW + px]);
        float py  = (float)(h + n/3) + offy;
        float pxf = (float)(px + n%3) + offx;
        float fy = floorf(py), fx = floorf(pxf);
        float lty = fminf(fmaxf(fy,     0.f),129.f);
        float ltx = fminf(fmaxf(fx,     0.f),129.f);
        float rby = fminf(fmaxf(fy+1.f, 0.f),129.f);
        float rbx = fminf(fmaxf(fx+1.f, 0.f),129.f);
        float pyc = fminf(fmaxf(py,     0.f),129.f);
        float pxc = fminf(fmaxf(pxf,    0.f),129.f);
        float ay = 1.f + (lty-pyc), by = 1.f - (rby-pyc);
        float ax = 1.f + (ltx-pxc), bx = 1.f - (rbx-pxc);
        float glt = ay*ax, glb = ay*bx, grt = by*ax, grb = by*bx;
        int base = ((int)lty*XW + (int)ltx)*64;
        int dxo  = ((int)rbx - (int)ltx)*64;
        int dyo  = ((int)rby - (int)lty)*XW*64;

        // stage B for this n (2048 u32 contiguous -> padded rows)
        const uint4* dsrc = (const uint4*)(dwb2 + n*2048);
        #pragma unroll
        for (int i=0;i<2;i++){
            int j = t + 256*i;
            int idx4 = j*4;
            int oc = idx4 >> 5, cp = idx4 & 31;
            *(uint4*)&Bsu[oc*36 + cp] = dsrc[j];
        }

        const unsigned short* fpx = fbase + base;
        #pragma unroll
        for (int u=0;u<2;u++){
            int sub = 2*kh + u;
            const unsigned short* fc = fpx + sub*16;
            unsigned LT[8], LB[8], RT[8], RB[8];
            *(uint4*)(LT)   = *(const uint4*)(fc);
            *(uint4*)(LT+4) = *(const uint4*)(fc+8);
            *(uint4*)(LB)   = *(const uint4*)(fc+dxo);
            *(uint4*)(LB+4) = *(const uint4*)(fc+dxo+8);
            *(uint4*)(RT)   = *(const uint4*)(fc+dyo);
            *(uint4*)(RT+4) = *(const uint4*)(fc+dyo+8);
            *(uint4*)(RB)   = *(const uint4*)(fc+dyo+dxo);
            *(uint4*)(RB+4) = *(const uint4*)(fc+dyo+dxo+8);
            unsigned pk[8];
            #pragma unroll
            for (int j=0;j<8;j++){
                float2 a = up2(LT[j]), bq = up2(LB[j]);
                float2 c = up2(RT[j]), dq = up2(RB[j]);
                float slo = glt*a.x + glb*bq.x + grt*c.x + grb*dq.x;
                float shi = glt*a.y + glb*bq.y + grt*c.y + grb*dq.y;
                pk[j] = pack2(slo, shi);
            }
            *(uint4*)&Asu[((sub*2+0)*128 + px)*4] = *(uint4*)pk;
            *(uint4*)&Asu[((sub*2+1)*128 + px)*4] = *(uint4*)(pk+4);
        }
        __syncthreads();
        const unsigned short* As16 = (const unsigned short*)Asu;
        const unsigned short* Bs16 = (const unsigned short*)Bsu;
        #pragma unroll
        for (int s=0;s<4;s++){
            s16x8 a  = *(const s16x8*)(As16 + ((s*2+half)*128 + 32*w + l31)*8);
            s16x8 b0 = *(const s16x8*)(Bs16 + (l31*36 + s*8 + half*4)*2);
            s16x8 b1 = *(const s16x8*)(Bs16 + ((32+l31)*36 + s*8 + half*4)*2);
            acc0 = __builtin_amdgcn_mfma_f32_32x32x16_bf16(a, b0, acc0, 0,0,0);
            acc1 = __builtin_amdgcn_mfma_f32_32x32x16_bf16(a, b1, acc1, 0,0,0);
        }
        __syncthreads();
    }

    // epilogue: +db, ep[px][oc] u16 == dout2 row layout, straight copy out
    unsigned short* ep = (unsigned short*)Asu;
    #pragma unroll
    for (int nt=0; nt<2; nt++){
        int oc = nt*32 + l31;
        float bias = db[oc];
        const f32x16& A = nt ? acc1 : acc0;
        #pragma unroll
        for (int rg=0; rg<4; rg++){
            int m0 = 32*w + 4*half + 8*rg;
            #pragma unroll
            for (int e=0;e<4;e++)
                ep[(m0+e)*64 + oc] = b16u(A[4*rg+e] + bias);
        }
    }
    __syncthreads();
    uint4* dst = (uint4*)((unsigned short*)dout2 + ((size_t)zb*128 + h)*(128*64));
    #pragma unroll
    for (int i=0;i<4;i++)
        dst[t + 256*i] = ((const uint4*)ep)[t + 256*i];
}

// ---------------------------------------------------------------------------
// K3b: 1x1 conv 256 -> 64 + cb + ReLU via bf16 MFMA. grid (128 h, 4 b).
// M=128 px, N=64, K=256 (4 d x 64 oc), A from NHWC dout2 (pipelined).
// ---------------------------------------------------------------------------
__global__ __launch_bounds__(256,2) void k_combine_mfma(
    const bf16* __restrict__ dout2,
    const unsigned* __restrict__ cwb2,  // [oc][cp128] u32
    const float* __restrict__ cb,
    float* __restrict__ out)
{
    int h = blockIdx.x, b = blockIdx.y;
    int t = threadIdx.x;
    int px = t & 127, hf = t >> 7;
    int lane = t & 63, w = t >> 6, l31 = lane & 31, half = lane >> 5;

    __shared__ unsigned Bsu[64*132];   // 33 KB, padded rows
    __shared__ unsigned Asu2[1024];    // 4 KB

    for (int i=t; i<8192; i+=256){
        int oc = i>>7, cp = i&127;
        Bsu[oc*132 + cp] = cwb2[i];
    }
    f32x16 acc0, acc1;
    #pragma unroll
    for (int e=0;e<16;e++){ acc0[e]=0.f; acc1[e]=0.f; }

    const unsigned short* dbase0 = (const unsigned short*)dout2;
    size_t rowsel = ((size_t)b*128 + h)*128 + px;   // within-slice (d varies)
    uint4 v = *(const uint4*)(dbase0 + ((size_t)0*4*128*128 + rowsel)*64 + hf*8);
    for (int kc=0; kc<16; kc++){
        *(uint4*)&Asu2[(hf*128+px)*4] = v;
        __syncthreads();
        if (kc < 15){
            int kn = kc+1;
            int d = kn>>2, c16 = kn&3;
            v = *(const uint4*)(dbase0 + ((size_t)d*4*128*128*64 + rowsel*64) + c16*16 + hf*8);
        }
        const unsigned short* As16 = (const unsigned short*)Asu2;
        const unsigned short* Bs16 = (const unsigned short*)Bsu;
        s16x8 a  = *(const s16x8*)(As16 + (half*128 + 32*w + l31)*8);
        s16x8 b0 = *(const s16x8*)(Bs16 + (l31*132 + kc*8 + half*4)*2);
        s16x8 b1 = *(const s16x8*)(Bs16 + ((32+l31)*132 + kc*8 + half*4)*2);
        acc0 = __builtin_amdgcn_mfma_f32_32x32x16_bf16(a, b0, acc0, 0,0,0);
        acc1 = __builtin_amdgcn_mfma_f32_32x32x16_bf16(a, b1, acc1, 0,0,0);
        __syncthreads();
    }
    float* ep = (float*)Bsu;   // [64 oc][132] f32 overlay (33 KB)
    #pragma unroll
    for (int nt=0; nt<2; nt++){
        int oc = nt*32 + l31;
        float bias = cb[oc];
        const f32x16& A = nt ? acc1 : acc0;
        #pragma unroll
        for (int rg=0; rg<4; rg++){
            int m0 = 32*w + 4*half + 8*rg;
            #pragma unroll
            for (int e=0;e<4;e++)
                ep[oc*132 + m0+e] = fmaxf(A[4*rg+e] + bias, 0.f);
        }
    }
    __syncthreads();
    for (int i=t; i<2048; i+=256){
        int oc = i>>5, sg = i&31;
        *(uint4*)&out[(((size_t)b*64+oc)*128 + h)*128 + sg*4] = *(const uint4*)&ep[oc*132 + sg*4];
    }
}

extern "C" void kernel_launch(void* const* d_in, const int* in_sizes, int n_in,
                              void* d_out, int out_size, void* d_ws, size_t ws_size,
                              hipStream_t stream) {
    const float* x  = (const float*)d_in[0];
    const float* w1 = (const float*)d_in[1];
    const float* b1 = (const float*)d_in[2];
    const float* w2 = (const float*)d_in[3];
    const float* b2 = (const float*)d_in[4];
    const float* w3 = (const float*)d_in[5];
    const float* b3 = (const float*)d_in[6];
    const float* w4 = (const float*)d_in[7];
    const float* b4 = (const float*)d_in[8];
    const float* pw = (const float*)d_in[9];
    const float* pb = (const float*)d_in[10];
    const float* dw = (const float*)d_in[11];
    const float* db = (const float*)d_in[12];
    const float* cw = (const float*)d_in[13];
    const float* cb = (const float*)d_in[14];
    float* out = (float*)d_out;

    bf16* feats2 = (bf16*)d_ws;                             // 16*FSL = 34.6 MB
    bf16* offs   = feats2 + (size_t)16*FSL;                 // 9.4 MB
    bf16* region2 = offs + (size_t)16*18*HW;
    bf16* dout2  = region2;                                 // 33.55 MB
    unsigned* xt  = (unsigned*)region2;                     // 21.2 MB (dead before dout2)
    unsigned* wbt = xt + (size_t)4*XTD*XTD*64;              // 0.59 MB (dead before dout2)
    unsigned* dwb2 = (unsigned*)(dout2 + (size_t)16*128*128*64);  // 73.7 KB
    unsigned* cwb2 = dwb2 + 18432;                          // 32.8 KB

    k_prep        <<<dim3(1704),    256, 0, stream>>>(w1,w2,w3,w4, dw, cw,
                                                      (uint4*)xt, wbt, dwb2, cwb2);
    k_xprep       <<<dim3(128,4),   256, 0, stream>>>(x, xt);
    k_branch_mfma <<<dim3(64,16),   256, 0, stream>>>(xt, wbt, b1,b2,b3,b4, feats2);
    k_offset_conv <<<dim3(128,16),  256, 0, stream>>>(feats2, pw, pb, offs);
    k_deform_mfma <<<dim3(2048),    256, 0, stream>>>(feats2, offs, dwb2, db, dout2);
    k_combine_mfma<<<dim3(128,4),   256, 0, stream>>>(dout2, cwb2, cb, out);
}

// Round 6
// 495.580 us; speedup vs baseline: 6.2557x; 1.1846x over previous
//
#include <hip/hip_runtime.h>
#include <hip/hip_bf16.h>

#define H 128
#define W 128
#define CIN 128
#define COUT 64
#define HW (H*W)
#define XW 130                    // padded spatial dim (y,x in [0,129])
#define FSL (XW*XW*64)            // feats2 elems per zb slice (NHWC bf16)
#define XTD 144                   // xt padded dim

typedef __hip_bfloat16 bf16;
typedef __attribute__((ext_vector_type(8)))  short s16x8;
typedef __attribute__((ext_vector_type(16))) float f32x16;

__device__ __forceinline__ float b2f(bf16 v){ return __bfloat162float(v); }
__device__ __forceinline__ bf16  f2b(float v){ return __float2bfloat16(v); }
__device__ __forceinline__ unsigned pack2(float a, float b){
    unsigned short ua = __builtin_bit_cast(unsigned short, f2b(a));
    unsigned short ub = __builtin_bit_cast(unsigned short, f2b(b));
    return (unsigned)ua | ((unsigned)ub << 16);
}
__device__ __forceinline__ unsigned short b16u(float v){
    return __builtin_bit_cast(unsigned short, f2b(v));
}
__device__ __forceinline__ float2 up2(unsigned u){
    float lo = __builtin_bit_cast(float, u << 16);
    float hi = __builtin_bit_cast(float, u & 0xFFFF0000u);
    return make_float2(lo, hi);
}

// ---------------------------------------------------------------------------
// k_prep: [0,1024) zero xt2; [1024,1600) wbt; [1600,1672) dwb2; [1672,1704) cwb2
// wbt layout: [d][cg 8][tap 9][oc 64][cpl 8] u32
// ---------------------------------------------------------------------------
__global__ __launch_bounds__(256) void k_prep(
    const float* __restrict__ w1, const float* __restrict__ w2,
    const float* __restrict__ w3, const float* __restrict__ w4,
    const float* __restrict__ dw, const float* __restrict__ cw,
    uint4* __restrict__ xt4, unsigned* __restrict__ wbt,
    unsigned* __restrict__ dwb2, unsigned* __restrict__ cwb2)
{
    int bid = blockIdx.x;
    int t = threadIdx.x;
    if (bid < 1024){
        const int n4 = (4*XTD*XTD*64)/4;        // 1327104
        for (int i = bid*256 + t; i < n4; i += 1024*256)
            xt4[i] = make_uint4(0,0,0,0);
    } else if (bid < 1600){
        int tid = (bid-1024)*256 + t;            // 147456 = 4*8*9*64*8
        int cpl = tid & 7;
        int oc  = (tid >> 3) & 63;
        int tap = (tid >> 9) % 9;
        int cg  = (tid / 4608) & 7;
        int d   = tid / 36864;
        const float* wt = (d==0)?w1:(d==1)?w2:(d==2)?w3:w4;
        int c = cg*8 + cpl;
        wbt[tid] = pack2(wt[((size_t)oc*CIN + 2*c  )*9 + tap],
                         wt[((size_t)oc*CIN + 2*c+1)*9 + tap]);
    } else if (bid < 1672){
        int i = (bid-1600)*256 + t;              // 18432: dwb2[n][oc][cp32]
        int n = i>>11, oc = (i>>5)&63, cp = i&31;
        dwb2[i] = pack2(dw[((size_t)oc*64 + 2*cp  )*9 + n],
                        dw[((size_t)oc*64 + 2*cp+1)*9 + n]);
    } else {
        int i = (bid-1672)*256 + t;              // 8192: cwb2[oc][cp128]
        int oc = i>>7, cp = i&127;
        cwb2[i] = pack2(cw[(size_t)oc*256 + 2*cp], cw[(size_t)oc*256 + 2*cp+1]);
    }
}

// ---------------------------------------------------------------------------
// xprep: xt2[b][cg 8][y+8][col+8][cpl 8] u32 (interior). grid (128 y, 4 b).
// ---------------------------------------------------------------------------
__global__ __launch_bounds__(256) void k_xprep(
    const float* __restrict__ x, unsigned* __restrict__ xt)
{
    int y = blockIdx.x, b = blockIdx.y;
    int t = threadIdx.x;
    __shared__ float xsm[64*131];
    for (int ci0 = 0; ci0 < 128; ci0 += 64){
        for (int i=0;i<32;i++){
            int idx = t + 256*i;
            int col = idx & 127, ci = idx >> 7;
            xsm[ci*131 + col] = x[(((size_t)b*CIN + ci0+ci)*H + y)*W + col];
        }
        __syncthreads();
        for (int i=0;i<16;i++){
            int idx = t + 256*i;                 // 4096 = 32 cpg x 128 col
            int cpg = idx & 31, col = idx >> 5;
            int cgg = (ci0 >> 4) + (cpg >> 3);
            int cpl = cpg & 7;
            unsigned u = pack2(xsm[(2*cpg)*131 + col], xsm[(2*cpg+1)*131 + col]);
            xt[((((size_t)b*8 + cgg)*XTD + y+8)*XTD + col+8)*8 + cpl] = u;
        }
        __syncthreads();
    }
}

// ---------------------------------------------------------------------------
// K1: dilated 3x3 conv via bf16 MFMA implicit GEMM. grid 1024 1-D with XCD
// swizzle: xcd=bid&7, j=bid>>3, zb=xcd+8*(j&1), hp=j>>1. Writes feats2 NHWC.
// Staging: contiguous uint4 loads from cg-major xt2/wbt + ds_write_b128.
// ---------------------------------------------------------------------------
__global__ __launch_bounds__(256,2) void k_branch_mfma(
    const unsigned* __restrict__ xt, const unsigned* __restrict__ wbt,
    const float* __restrict__ b1, const float* __restrict__ b2,
    const float* __restrict__ b3, const float* __restrict__ b4,
    bf16* __restrict__ feats2)
{
    int bid = blockIdx.x;
    int xcd = bid & 7;
    int j   = bid >> 3;
    int zb  = xcd + 8*(j & 1);
    int hp  = j >> 1;
    int d = zb >> 2, b = zb & 3;
    int dil = 2*d + 1;
    int h0 = hp*2;
    const float* bs = (d==0)?b1:(d==1)?b2:(d==2)?b3:b4;
    const float scale = (float)dil;

    __shared__ unsigned smem[10368 + 6912];
    unsigned* As = smem;                          // [(row6*144+s)*12 + cp]
    unsigned* Bs = smem + 10368;                  // [(tap*64+oc)*12 + cp]
    const unsigned short* As16 = (const unsigned short*)As;
    const unsigned short* Bs16 = (const unsigned short*)Bs;

    int t = threadIdx.x;
    int lane = t & 63;
    int w = t >> 6;
    int l31 = lane & 31;
    int half = lane >> 5;

    bf16* fb = feats2 + (size_t)zb*FSL;
    if (t < 32){
        int yy = h0 + 1 + (t>>4);
        int side = (t>>3)&1;
        int q = t & 7;
        uint4 z = make_uint4(0,0,0,0);
        *(uint4*)((unsigned short*)fb + ((size_t)yy*XW + side*129)*64 + q*8) = z;
    }
    if (hp == 0){
        uint4 z = make_uint4(0,0,0,0);
        for (int i=t; i<2080; i+=256){
            int row = i / 1040;
            int r = i % 1040;
            int xx = r >> 3, q = r & 7;
            *(uint4*)((unsigned short*)fb + ((size_t)(row*129)*XW + xx)*64 + q*8) = z;
        }
    }

    f32x16 acc[2][2];
    #pragma unroll
    for (int i=0;i<2;i++)
      #pragma unroll
      for (int jj=0;jj<2;jj++)
        #pragma unroll
        for (int e=0;e<16;e++) acc[i][jj][e] = 0.f;

    const unsigned* xtb_b = xt + (size_t)b*8*XTD*XTD*8;
    int r = w >> 1;
    int pxb = (w & 1) * 64;

    for (int cg=0; cg<8; cg++){
        const unsigned* xs_cg = xtb_b + (size_t)cg*XTD*XTD*8;
        #pragma unroll
        for (int i=0;i<7;i++){
            int idx4 = t + 256*i;                 // 1728 = 6*144*2
            if (idx4 < 1728){
                int cp4 = idx4 & 1;
                int s   = (idx4 >> 1) % 144;
                int row6= idx4 / 288;
                int ky = row6 >> 1, rr = row6 & 1;
                int yy = h0 + rr + (ky-1)*dil + 8;
                uint4 v = *(const uint4*)(xs_cg + ((size_t)yy*XTD + (s + 8 - dil))*8 + cp4*4);
                *(uint4*)&As[(row6*144 + s)*12 + cp4*4] = v;
            }
        }
        const unsigned* wb_cg = wbt + ((size_t)d*8 + cg)*4608;
        #pragma unroll
        for (int i=0;i<5;i++){
            int idx4 = t + 256*i;                 // 1152 = 9*64*2
            if (idx4 < 1152){
                int cp4 = idx4 & 1;
                int oc  = (idx4 >> 1) & 63;
                int tap = idx4 >> 7;
                uint4 v = *(const uint4*)(wb_cg + ((size_t)tap*64 + oc)*8 + cp4*4);
                *(uint4*)&Bs[(tap*64 + oc)*12 + cp4*4] = v;
            }
        }
        __syncthreads();
        #pragma unroll
        for (int tap=0; tap<9; tap++){
            int ky = tap/3, kx = tap%3;
            int rowb = (ky*2 + r)*144;
            s16x8 a0 = *(const s16x8*)(As16 + (rowb + pxb      + l31 + kx*dil)*24 + half*8);
            s16x8 a1 = *(const s16x8*)(As16 + (rowb + pxb + 32 + l31 + kx*dil)*24 + half*8);
            s16x8 bb0 = *(const s16x8*)(Bs16 + (tap*64      + l31)*24 + half*8);
            s16x8 bb1 = *(const s16x8*)(Bs16 + (tap*64 + 32 + l31)*24 + half*8);
            acc[0][0] = __builtin_amdgcn_mfma_f32_32x32x16_bf16(a0, bb0, acc[0][0], 0,0,0);
            acc[0][1] = __builtin_amdgcn_mfma_f32_32x32x16_bf16(a0, bb1, acc[0][1], 0,0,0);
            acc[1][0] = __builtin_amdgcn_mfma_f32_32x32x16_bf16(a1, bb0, acc[1][0], 0,0,0);
            acc[1][1] = __builtin_amdgcn_mfma_f32_32x32x16_bf16(a1, bb1, acc[1][1], 0,0,0);
        }
        __syncthreads();
    }

    // epilogue: bias+scale, stage ep[m 256][oc 64] u16, NHWC vector stores
    unsigned short* ep = (unsigned short*)smem;
    float bias0 = bs[l31], bias1 = bs[32 + l31];
    #pragma unroll
    for (int i=0;i<2;i++){
      #pragma unroll
      for (int jj=0;jj<2;jj++){
        int oc = jj*32 + l31;
        float bj = jj ? bias1 : bias0;
        #pragma unroll
        for (int rg=0; rg<4; rg++){
            int m0 = 64*w + 32*i + 8*rg + 4*half;
            #pragma unroll
            for (int e=0;e<4;e++)
                ep[(m0+e)*64 + oc] = b16u((acc[i][jj][4*rg+e] + bj)*scale);
        }
      }
    }
    __syncthreads();
    {
        int row = t >> 7, pxm = t & 127;
        unsigned short* drow = (unsigned short*)fb + ((size_t)(h0+1+row)*XW + pxm + 1)*64;
        const unsigned short* srow = ep + t*64;
        #pragma unroll
        for (int q=0;q<8;q++)
            *(uint4*)(drow + q*8) = *(const uint4*)(srow + q*8);
    }
}

// ---------------------------------------------------------------------------
// K2: 3x3 conv pad=1, 64 -> 18 (offsets) from NHWC feats2.
// grid (128 h, 16 zb), block 256.
// ---------------------------------------------------------------------------
__global__ __launch_bounds__(256,4) void k_offset_conv(
    const bf16* __restrict__ feats2,
    const float* __restrict__ pw, const float* __restrict__ pb,
    bf16* __restrict__ offs)
{
    int h  = blockIdx.x;
    int zb = blockIdx.y;
    __shared__ float xs[8*3*132];
    __shared__ float ws2[8*9*24];
    int t = threadIdx.x;
    int w = t & 127;
    int half = t >> 7;
    float acc[9];
    #pragma unroll
    for (int j=0;j<9;j++) acc[j]=0.f;
    const unsigned short* fin = (const unsigned short*)(feats2 + (size_t)zb*FSL);
    for (int c0=0; c0<COUT; c0+=8){
        for (int idx=t; idx<390; idx+=256){
            int ky = idx/130, col = idx%130;
            unsigned u[4];
            *(uint4*)u = *(const uint4*)(fin + ((size_t)(h+ky)*XW + col)*64 + c0);
            #pragma unroll
            for (int k=0;k<4;k++){
                float2 f = up2(u[k]);
                xs[((2*k  )*3+ky)*132 + col] = f.x;
                xs[((2*k+1)*3+ky)*132 + col] = f.y;
            }
        }
        for (int idx=t; idx<1296; idx+=256){
            int c = idx/162, r = idx%162, tap = r/18, o = r%18;
            ws2[(c*9+tap)*24 + (o/9)*12 + (o%9)] = pw[((size_t)o*COUT + c0+c)*9 + tap];
        }
        __syncthreads();
        #pragma unroll
        for (int c=0;c<8;c++)
          #pragma unroll
          for (int ky=0;ky<3;ky++)
            #pragma unroll
            for (int kx=0;kx<3;kx++){
               float xv = xs[(c*3+ky)*132 + w + kx];
               const float* wbase = &ws2[(c*9+ky*3+kx)*24 + half*12];
               float4 wa = *(const float4*)wbase;
               float4 wb = *(const float4*)(wbase+4);
               float w8 = wbase[8];
               acc[0]+=wa.x*xv; acc[1]+=wa.y*xv; acc[2]+=wa.z*xv; acc[3]+=wa.w*xv;
               acc[4]+=wb.x*xv; acc[5]+=wb.y*xv; acc[6]+=wb.z*xv; acc[7]+=wb.w*xv;
               acc[8]+=w8*xv;
            }
        __syncthreads();
    }
    #pragma unroll
    for (int j=0;j<9;j++){
        int oc = half*9+j;
        offs[((size_t)zb*18 + oc)*HW + h*W + w] = f2b(acc[j] + pb[oc]);
    }
}

// ---------------------------------------------------------------------------
// K3a: deform sampling + dw einsum via bf16 MFMA, NHWC feats.
// grid 2048 1-D, XCD swizzle. Writes dout2 NHWC [zb][h][px][oc].
// ---------------------------------------------------------------------------
__global__ __launch_bounds__(256,4) void k_deform_mfma(
    const bf16* __restrict__ feats2,
    const bf16* __restrict__ offs,
    const unsigned* __restrict__ dwb2,  // [n][oc][cp32] u32
    const float* __restrict__ db,
    bf16* __restrict__ dout2)
{
    int bid = blockIdx.x;
    int xcd  = bid & 7;
    int h    = (bid >> 3) & 127;
    int pass = bid >> 10;
    int zb   = xcd + 8*pass;

    int t = threadIdx.x;
    int px = t & 127, kh = t >> 7;
    int lane = t & 63, w = t >> 6;
    int l31 = lane & 31, half = lane >> 5;

    __shared__ unsigned Asu[4096];   // [sub2half 8][px 128][4 u32]
    __shared__ unsigned Bsu[2304];   // [oc 64][36 pad]

    const bf16* obase = offs + (size_t)zb*18*HW + h*W;
    const unsigned short* fbase = (const unsigned short*)(feats2 + (size_t)zb*FSL);

    f32x16 acc0, acc1;
    #pragma unroll
    for (int e=0;e<16;e++){ acc0[e]=0.f; acc1[e]=0.f; }

    for (int n=0; n<9; n++){
        float offy = b2f(obase[n*HW + px]);
        float offx = b2f(obase[(n+9)*HW + px]);
        float py  = (float)(h + n/3) + offy;
        float pxf = (float)(px + n%3) + offx;
        float fy = floorf(py), fx = floorf(pxf);
        float lty = fminf(fmaxf(fy,     0.f),129.f);
        float ltx = fminf(fmaxf(fx,     0.f),129.f);
        float rby = fminf(fmaxf(fy+1.f, 0.f),129.f);
        float rbx = fminf(fmaxf(fx+1.f, 0.f),129.f);
        float pyc = fminf(fmaxf(py,     0.f),129.f);
        float pxc = fminf(fmaxf(pxf,    0.f),129.f);
        float ay = 1.f + (lty-pyc), by = 1.f - (rby-pyc);
        float ax = 1.f + (ltx-pxc), bx = 1.f - (rbx-pxc);
        float glt = ay*ax, glb = ay*bx, grt = by*ax, grb = by*bx;
        int base = ((int)lty*XW + (int)ltx)*64;
        int dxo  = ((int)rbx - (int)ltx)*64;
        int dyo  = ((int)rby - (int)lty)*XW*64;

        const uint4* dsrc = (const uint4*)(dwb2 + n*2048);
        #pragma unroll
        for (int i=0;i<2;i++){
            int j = t + 256*i;
            int idx4 = j*4;
            int oc = idx4 >> 5, cp = idx4 & 31;
            *(uint4*)&Bsu[oc*36 + cp] = dsrc[j];
        }

        const unsigned short* fpx = fbase + base;
        #pragma unroll
        for (int u=0;u<2;u++){
            int sub = 2*kh + u;
            const unsigned short* fc = fpx + sub*16;
            unsigned LT[8], LB[8], RT[8], RB[8];
            *(uint4*)(LT)   = *(const uint4*)(fc);
            *(uint4*)(LT+4) = *(const uint4*)(fc+8);
            *(uint4*)(LB)   = *(const uint4*)(fc+dxo);
            *(uint4*)(LB+4) = *(const uint4*)(fc+dxo+8);
            *(uint4*)(RT)   = *(const uint4*)(fc+dyo);
            *(uint4*)(RT+4) = *(const uint4*)(fc+dyo+8);
            *(uint4*)(RB)   = *(const uint4*)(fc+dyo+dxo);
            *(uint4*)(RB+4) = *(const uint4*)(fc+dyo+dxo+8);
            unsigned pk[8];
            #pragma unroll
            for (int jq=0;jq<8;jq++){
                float2 a = up2(LT[jq]), bq = up2(LB[jq]);
                float2 c = up2(RT[jq]), dq = up2(RB[jq]);
                float slo = glt*a.x + glb*bq.x + grt*c.x + grb*dq.x;
                float shi = glt*a.y + glb*bq.y + grt*c.y + grb*dq.y;
                pk[jq] = pack2(slo, shi);
            }
            *(uint4*)&Asu[((sub*2+0)*128 + px)*4] = *(uint4*)pk;
            *(uint4*)&Asu[((sub*2+1)*128 + px)*4] = *(uint4*)(pk+4);
        }
        __syncthreads();
        const unsigned short* As16 = (const unsigned short*)Asu;
        const unsigned short* Bs16 = (const unsigned short*)Bsu;
        #pragma unroll
        for (int s=0;s<4;s++){
            s16x8 a  = *(const s16x8*)(As16 + ((s*2+half)*128 + 32*w + l31)*8);
            s16x8 b0 = *(const s16x8*)(Bs16 + (l31*36 + s*8 + half*4)*2);
            s16x8 b1 = *(const s16x8*)(Bs16 + ((32+l31)*36 + s*8 + half*4)*2);
            acc0 = __builtin_amdgcn_mfma_f32_32x32x16_bf16(a, b0, acc0, 0,0,0);
            acc1 = __builtin_amdgcn_mfma_f32_32x32x16_bf16(a, b1, acc1, 0,0,0);
        }
        __syncthreads();
    }

    unsigned short* ep = (unsigned short*)Asu;
    #pragma unroll
    for (int nt=0; nt<2; nt++){
        int oc = nt*32 + l31;
        float bias = db[oc];
        const f32x16& A = nt ? acc1 : acc0;
        #pragma unroll
        for (int rg=0; rg<4; rg++){
            int m0 = 32*w + 4*half + 8*rg;
            #pragma unroll
            for (int e=0;e<4;e++)
                ep[(m0+e)*64 + oc] = b16u(A[4*rg+e] + bias);
        }
    }
    __syncthreads();
    uint4* dst = (uint4*)((unsigned short*)dout2 + ((size_t)zb*128 + h)*(128*64));
    #pragma unroll
    for (int i=0;i<4;i++)
        dst[t + 256*i] = ((const uint4*)ep)[t + 256*i];
}

// ---------------------------------------------------------------------------
// K3b: 1x1 conv 256 -> 64 + cb + ReLU via bf16 MFMA. grid (128 h, 4 b).
// ---------------------------------------------------------------------------
__global__ __launch_bounds__(256,2) void k_combine_mfma(
    const bf16* __restrict__ dout2,
    const unsigned* __restrict__ cwb2,  // [oc][cp128] u32
    const float* __restrict__ cb,
    float* __restrict__ out)
{
    int h = blockIdx.x, b = blockIdx.y;
    int t = threadIdx.x;
    int px = t & 127, hf = t >> 7;
    int lane = t & 63, w = t >> 6, l31 = lane & 31, half = lane >> 5;

    __shared__ unsigned Bsu[64*132];
    __shared__ unsigned Asu2[1024];

    for (int i=t; i<8192; i+=256){
        int oc = i>>7, cp = i&127;
        Bsu[oc*132 + cp] = cwb2[i];
    }
    f32x16 acc0, acc1;
    #pragma unroll
    for (int e=0;e<16;e++){ acc0[e]=0.f; acc1[e]=0.f; }

    const unsigned short* dbase0 = (const unsigned short*)dout2;
    size_t rowsel = ((size_t)b*128 + h)*128 + px;
    uint4 v = *(const uint4*)(dbase0 + rowsel*64 + hf*8);
    for (int kc=0; kc<16; kc++){
        *(uint4*)&Asu2[(hf*128+px)*4] = v;
        __syncthreads();
        if (kc < 15){
            int kn = kc+1;
            int d = kn>>2, c16 = kn&3;
            v = *(const uint4*)(dbase0 + ((size_t)d*4*128*128*64 + rowsel*64) + c16*16 + hf*8);
        }
        const unsigned short* As16 = (const unsigned short*)Asu2;
        const unsigned short* Bs16 = (const unsigned short*)Bsu;
        s16x8 a  = *(const s16x8*)(As16 + (half*128 + 32*w + l31)*8);
        s16x8 b0 = *(const s16x8*)(Bs16 + (l31*132 + kc*8 + half*4)*2);
        s16x8 b1 = *(const s16x8*)(Bs16 + ((32+l31)*132 + kc*8 + half*4)*2);
        acc0 = __builtin_amdgcn_mfma_f32_32x32x16_bf16(a, b0, acc0, 0,0,0);
        acc1 = __builtin_amdgcn_mfma_f32_32x32x16_bf16(a, b1, acc1, 0,0,0);
        __syncthreads();
    }
    float* ep = (float*)Bsu;
    #pragma unroll
    for (int nt=0; nt<2; nt++){
        int oc = nt*32 + l31;
        float bias = cb[oc];
        const f32x16& A = nt ? acc1 : acc0;
        #pragma unroll
        for (int rg=0; rg<4; rg++){
            int m0 = 32*w + 4*half + 8*rg;
            #pragma unroll
            for (int e=0;e<4;e++)
                ep[oc*132 + m0+e] = fmaxf(A[4*rg+e] + bias, 0.f);
        }
    }
    __syncthreads();
    for (int i=t; i<2048; i+=256){
        int oc = i>>5, sg = i&31;
        *(uint4*)&out[(((size_t)b*64+oc)*128 + h)*128 + sg*4] = *(const uint4*)&ep[oc*132 + sg*4];
    }
}

extern "C" void kernel_launch(void* const* d_in, const int* in_sizes, int n_in,
                              void* d_out, int out_size, void* d_ws, size_t ws_size,
                              hipStream_t stream) {
    const float* x  = (const float*)d_in[0];
    const float* w1 = (const float*)d_in[1];
    const float* b1 = (const float*)d_in[2];
    const float* w2 = (const float*)d_in[3];
    const float* b2 = (const float*)d_in[4];
    const float* w3 = (const float*)d_in[5];
    const float* b3 = (const float*)d_in[6];
    const float* w4 = (const float*)d_in[7];
    const float* b4 = (const float*)d_in[8];
    const float* pw = (const float*)d_in[9];
    const float* pb = (const float*)d_in[10];
    const float* dw = (const float*)d_in[11];
    const float* db = (const float*)d_in[12];
    const float* cw = (const float*)d_in[13];
    const float* cb = (const float*)d_in[14];
    float* out = (float*)d_out;

    bf16* feats2 = (bf16*)d_ws;                             // 34.6 MB
    bf16* offs   = feats2 + (size_t)16*FSL;                 // 9.4 MB
    bf16* region2 = offs + (size_t)16*18*HW;
    bf16* dout2  = region2;                                 // 33.55 MB
    unsigned* xt  = (unsigned*)region2;                     // 21.2 MB (dead before dout2)
    unsigned* wbt = xt + (size_t)4*8*XTD*XTD*8;             // 0.59 MB (dead before dout2)
    unsigned* dwb2 = (unsigned*)(dout2 + (size_t)16*128*128*64);  // 73.7 KB
    unsigned* cwb2 = dwb2 + 18432;                          // 32.8 KB

    k_prep        <<<dim3(1704),    256, 0, stream>>>(w1,w2,w3,w4, dw, cw,
                                                      (uint4*)xt, wbt, dwb2, cwb2);
    k_xprep       <<<dim3(128,4),   256, 0, stream>>>(x, xt);
    k_branch_mfma <<<dim3(1024),    256, 0, stream>>>(xt, wbt, b1,b2,b3,b4, feats2);
    k_offset_conv <<<dim3(128,16),  256, 0, stream>>>(feats2, pw, pb, offs);
    k_deform_mfma <<<dim3(2048),    256, 0, stream>>>(feats2, offs, dwb2, db, dout2);
    k_combine_mfma<<<dim3(128,4),   256, 0, stream>>>(dout2, cwb2, cb, out);
}

// Round 7
// 391.284 us; speedup vs baseline: 7.9231x; 1.2665x over previous
//
#include <hip/hip_runtime.h>
#include <hip/hip_bf16.h>

#define H 128
#define W 128
#define CIN 128
#define COUT 64
#define HW (H*W)
#define XW 130                    // padded spatial dim (y,x in [0,129])
#define FSL (XW*XW*64)            // feats2 elems per zb slice (NHWC bf16)
#define XTD 144                   // xt padded dim

typedef __hip_bfloat16 bf16;
typedef __attribute__((ext_vector_type(8)))  short s16x8;
typedef __attribute__((ext_vector_type(16))) float f32x16;

__device__ __forceinline__ float b2f(bf16 v){ return __bfloat162float(v); }
__device__ __forceinline__ bf16  f2b(float v){ return __float2bfloat16(v); }
__device__ __forceinline__ unsigned pack2(float a, float b){
    unsigned short ua = __builtin_bit_cast(unsigned short, f2b(a));
    unsigned short ub = __builtin_bit_cast(unsigned short, f2b(b));
    return (unsigned)ua | ((unsigned)ub << 16);
}
__device__ __forceinline__ unsigned short b16u(float v){
    return __builtin_bit_cast(unsigned short, f2b(v));
}
__device__ __forceinline__ float2 up2(unsigned u){
    float lo = __builtin_bit_cast(float, u << 16);
    float hi = __builtin_bit_cast(float, u & 0xFFFF0000u);
    return make_float2(lo, hi);
}

// ---------------------------------------------------------------------------
// k_prep: [0,1024) zero xt2; [1024,1600) wbt; [1600,1672) dwb2;
//         [1672,1704) cwb2; [1704,1740) pwb
// wbt: [d][cg 8][tap 9][oc 64][cpl 8] u32
// pwb: [tap 9][cq 4][hf 2][oc 32][cl 4] u32  (oc>=18 zero)
// ---------------------------------------------------------------------------
__global__ __launch_bounds__(256) void k_prep(
    const float* __restrict__ w1, const float* __restrict__ w2,
    const float* __restrict__ w3, const float* __restrict__ w4,
    const float* __restrict__ dw, const float* __restrict__ cw,
    const float* __restrict__ pw,
    uint4* __restrict__ xt4, unsigned* __restrict__ wbt,
    unsigned* __restrict__ dwb2, unsigned* __restrict__ cwb2,
    unsigned* __restrict__ pwb)
{
    int bid = blockIdx.x;
    int t = threadIdx.x;
    if (bid < 1024){
        const int n4 = (4*XTD*XTD*64)/4;        // 1327104
        for (int i = bid*256 + t; i < n4; i += 1024*256)
            xt4[i] = make_uint4(0,0,0,0);
    } else if (bid < 1600){
        int tid = (bid-1024)*256 + t;            // 147456 = 4*8*9*64*8
        int cpl = tid & 7;
        int oc  = (tid >> 3) & 63;
        int tap = (tid >> 9) % 9;
        int cg  = (tid / 4608) & 7;
        int d   = tid / 36864;
        const float* wt = (d==0)?w1:(d==1)?w2:(d==2)?w3:w4;
        int c = cg*8 + cpl;
        wbt[tid] = pack2(wt[((size_t)oc*CIN + 2*c  )*9 + tap],
                         wt[((size_t)oc*CIN + 2*c+1)*9 + tap]);
    } else if (bid < 1672){
        int i = (bid-1600)*256 + t;              // 18432: dwb2[n][oc][cp32]
        int n = i>>11, oc = (i>>5)&63, cp = i&31;
        dwb2[i] = pack2(dw[((size_t)oc*64 + 2*cp  )*9 + n],
                        dw[((size_t)oc*64 + 2*cp+1)*9 + n]);
    } else if (bid < 1704){
        int i = (bid-1672)*256 + t;              // 8192: cwb2[oc][cp128]
        int oc = i>>7, cp = i&127;
        cwb2[i] = pack2(cw[(size_t)oc*256 + 2*cp], cw[(size_t)oc*256 + 2*cp+1]);
    } else {
        int i = (bid-1704)*256 + t;              // 9216
        int cl = i & 3, oc = (i>>2)&31, hf = (i>>7)&1, cq = (i>>8)&3, tap = i>>10;
        int c = cq*16 + hf*8 + cl*2;
        unsigned v = 0u;
        if (oc < 18)
            v = pack2(pw[((size_t)oc*64 + c  )*9 + tap],
                      pw[((size_t)oc*64 + c+1)*9 + tap]);
        pwb[i] = v;
    }
}

// ---------------------------------------------------------------------------
// xprep: xt2[b][cg 8][y+8][col+8][cpl 8] u32 (interior). grid (128 y, 4 b).
// ---------------------------------------------------------------------------
__global__ __launch_bounds__(256) void k_xprep(
    const float* __restrict__ x, unsigned* __restrict__ xt)
{
    int y = blockIdx.x, b = blockIdx.y;
    int t = threadIdx.x;
    __shared__ float xsm[64*131];
    for (int ci0 = 0; ci0 < 128; ci0 += 64){
        for (int i=0;i<32;i++){
            int idx = t + 256*i;
            int col = idx & 127, ci = idx >> 7;
            xsm[ci*131 + col] = x[(((size_t)b*CIN + ci0+ci)*H + y)*W + col];
        }
        __syncthreads();
        for (int i=0;i<16;i++){
            int idx = t + 256*i;
            int cpg = idx & 31, col = idx >> 5;
            int cgg = (ci0 >> 4) + (cpg >> 3);
            int cpl = cpg & 7;
            unsigned u = pack2(xsm[(2*cpg)*131 + col], xsm[(2*cpg+1)*131 + col]);
            xt[((((size_t)b*8 + cgg)*XTD + y+8)*XTD + col+8)*8 + cpl] = u;
        }
        __syncthreads();
    }
}

// ---------------------------------------------------------------------------
// K1: dilated 3x3 conv via bf16 MFMA implicit GEMM. grid 1024 1-D, XCD swizzle.
// ---------------------------------------------------------------------------
__global__ __launch_bounds__(256,2) void k_branch_mfma(
    const unsigned* __restrict__ xt, const unsigned* __restrict__ wbt,
    const float* __restrict__ b1, const float* __restrict__ b2,
    const float* __restrict__ b3, const float* __restrict__ b4,
    bf16* __restrict__ feats2)
{
    int bid = blockIdx.x;
    int xcd = bid & 7;
    int j   = bid >> 3;
    int zb  = xcd + 8*(j & 1);
    int hp  = j >> 1;
    int d = zb >> 2, b = zb & 3;
    int dil = 2*d + 1;
    int h0 = hp*2;
    const float* bs = (d==0)?b1:(d==1)?b2:(d==2)?b3:b4;
    const float scale = (float)dil;

    __shared__ unsigned smem[10368 + 6912];
    unsigned* As = smem;
    unsigned* Bs = smem + 10368;
    const unsigned short* As16 = (const unsigned short*)As;
    const unsigned short* Bs16 = (const unsigned short*)Bs;

    int t = threadIdx.x;
    int lane = t & 63;
    int w = t >> 6;
    int l31 = lane & 31;
    int half = lane >> 5;

    bf16* fb = feats2 + (size_t)zb*FSL;
    if (t < 32){
        int yy = h0 + 1 + (t>>4);
        int side = (t>>3)&1;
        int q = t & 7;
        uint4 z = make_uint4(0,0,0,0);
        *(uint4*)((unsigned short*)fb + ((size_t)yy*XW + side*129)*64 + q*8) = z;
    }
    if (hp == 0){
        uint4 z = make_uint4(0,0,0,0);
        for (int i=t; i<2080; i+=256){
            int row = i / 1040;
            int r = i % 1040;
            int xx = r >> 3, q = r & 7;
            *(uint4*)((unsigned short*)fb + ((size_t)(row*129)*XW + xx)*64 + q*8) = z;
        }
    }

    f32x16 acc[2][2];
    #pragma unroll
    for (int i=0;i<2;i++)
      #pragma unroll
      for (int jj=0;jj<2;jj++)
        #pragma unroll
        for (int e=0;e<16;e++) acc[i][jj][e] = 0.f;

    const unsigned* xtb_b = xt + (size_t)b*8*XTD*XTD*8;
    int r = w >> 1;
    int pxb = (w & 1) * 64;

    for (int cg=0; cg<8; cg++){
        const unsigned* xs_cg = xtb_b + (size_t)cg*XTD*XTD*8;
        #pragma unroll
        for (int i=0;i<7;i++){
            int idx4 = t + 256*i;
            if (idx4 < 1728){
                int cp4 = idx4 & 1;
                int s   = (idx4 >> 1) % 144;
                int row6= idx4 / 288;
                int ky = row6 >> 1, rr = row6 & 1;
                int yy = h0 + rr + (ky-1)*dil + 8;
                uint4 v = *(const uint4*)(xs_cg + ((size_t)yy*XTD + (s + 8 - dil))*8 + cp4*4);
                *(uint4*)&As[(row6*144 + s)*12 + cp4*4] = v;
            }
        }
        const unsigned* wb_cg = wbt + ((size_t)d*8 + cg)*4608;
        #pragma unroll
        for (int i=0;i<5;i++){
            int idx4 = t + 256*i;
            if (idx4 < 1152){
                int cp4 = idx4 & 1;
                int oc  = (idx4 >> 1) & 63;
                int tap = idx4 >> 7;
                uint4 v = *(const uint4*)(wb_cg + ((size_t)tap*64 + oc)*8 + cp4*4);
                *(uint4*)&Bs[(tap*64 + oc)*12 + cp4*4] = v;
            }
        }
        __syncthreads();
        #pragma unroll
        for (int tap=0; tap<9; tap++){
            int ky = tap/3, kx = tap%3;
            int rowb = (ky*2 + r)*144;
            s16x8 a0 = *(const s16x8*)(As16 + (rowb + pxb      + l31 + kx*dil)*24 + half*8);
            s16x8 a1 = *(const s16x8*)(As16 + (rowb + pxb + 32 + l31 + kx*dil)*24 + half*8);
            s16x8 bb0 = *(const s16x8*)(Bs16 + (tap*64      + l31)*24 + half*8);
            s16x8 bb1 = *(const s16x8*)(Bs16 + (tap*64 + 32 + l31)*24 + half*8);
            acc[0][0] = __builtin_amdgcn_mfma_f32_32x32x16_bf16(a0, bb0, acc[0][0], 0,0,0);
            acc[0][1] = __builtin_amdgcn_mfma_f32_32x32x16_bf16(a0, bb1, acc[0][1], 0,0,0);
            acc[1][0] = __builtin_amdgcn_mfma_f32_32x32x16_bf16(a1, bb0, acc[1][0], 0,0,0);
            acc[1][1] = __builtin_amdgcn_mfma_f32_32x32x16_bf16(a1, bb1, acc[1][1], 0,0,0);
        }
        __syncthreads();
    }

    unsigned short* ep = (unsigned short*)smem;
    float bias0 = bs[l31], bias1 = bs[32 + l31];
    #pragma unroll
    for (int i=0;i<2;i++){
      #pragma unroll
      for (int jj=0;jj<2;jj++){
        int oc = jj*32 + l31;
        float bj = jj ? bias1 : bias0;
        #pragma unroll
        for (int rg=0; rg<4; rg++){
            int m0 = 64*w + 32*i + 8*rg + 4*half;
            #pragma unroll
            for (int e=0;e<4;e++)
                ep[(m0+e)*64 + oc] = b16u((acc[i][jj][4*rg+e] + bj)*scale);
        }
      }
    }
    __syncthreads();
    {
        int row = t >> 7, pxm = t & 127;
        unsigned short* drow = (unsigned short*)fb + ((size_t)(h0+1+row)*XW + pxm + 1)*64;
        const unsigned short* srow = ep + t*64;
        #pragma unroll
        for (int q=0;q<8;q++)
            *(uint4*)(drow + q*8) = *(const uint4*)(srow + q*8);
    }
}

// ---------------------------------------------------------------------------
// K2: 3x3 conv pad=1, 64 -> 18 (offsets) via bf16 MFMA. grid 2048 1-D with
// XCD swizzle. M=128 px, N=18 (pad 32), K=576 (tap-major, 36 k-steps).
// All 64 ch x 3 rows staged in LDS ONCE (each feats2 line fetched once).
// B frags read from prepped global pwb (wave-uniform, L1-resident).
// ---------------------------------------------------------------------------
__global__ __launch_bounds__(256,2) void k_offset_mfma(
    const bf16* __restrict__ feats2,
    const unsigned* __restrict__ pwb,   // [tap][cq][hf][oc32][cl4] u32
    const float* __restrict__ pb,
    bf16* __restrict__ offs)
{
    int bid = blockIdx.x;
    int xcd  = bid & 7;
    int h    = (bid >> 3) & 127;
    int pass = bid >> 10;
    int zb   = xcd + 8*pass;

    int t = threadIdx.x;
    int lane = t & 63, w = t >> 6;
    int l31 = lane & 31, half = lane >> 5;

    __shared__ unsigned short xs[3*132*68];   // [ky][col 130(pad132)][c 68] = 53.9 KB

    const unsigned short* fin = (const unsigned short*)(feats2 + (size_t)zb*FSL);
    // stage 3 rows x 130 cols x 64 ch, contiguous per row
    for (int i=t; i<3120; i+=256){
        int row = i / 1040;
        int r   = i % 1040;
        int col = r >> 3, q = r & 7;
        uint4 v = *(const uint4*)(fin + ((size_t)(h+row)*XW + col)*64 + q*8);
        *(uint4*)&xs[(row*132 + col)*68 + q*8] = v;
    }
    __syncthreads();

    f32x16 acc;
    #pragma unroll
    for (int e=0;e<16;e++) acc[e] = 0.f;

    int pxw = 32*w + l31;                     // this lane's pixel (m)
    #pragma unroll
    for (int tap=0; tap<9; tap++){
        int ky = tap/3, kx = tap%3;
        const unsigned short* arow = &xs[(ky*132 + pxw + kx)*68 + half*8];
        const unsigned* brow = pwb + (((size_t)tap*4)*2 + half)*128 + l31*4;
        #pragma unroll
        for (int cq=0; cq<4; cq++){
            s16x8 a  = *(const s16x8*)(arow + cq*16);
            s16x8 b0 = *(const s16x8*)(brow + cq*256);
            acc = __builtin_amdgcn_mfma_f32_32x32x16_bf16(a, b0, acc, 0,0,0);
        }
    }
    __syncthreads();

    // epilogue: +pb, transpose via LDS, coalesced stores (18 oc x 128 px)
    unsigned short* ep = (unsigned short*)xs;   // [oc 18][132 pad]
    if (l31 < 18){
        float bias = pb[l31];
        #pragma unroll
        for (int rg=0; rg<4; rg++){
            int m0 = 32*w + 4*half + 8*rg;
            #pragma unroll
            for (int e=0;e<4;e++)
                ep[l31*132 + m0+e] = b16u(acc[4*rg+e] + bias);
        }
    }
    __syncthreads();
    unsigned short* obase = (unsigned short*)(offs + (size_t)zb*18*HW) ;
    for (int i=t; i<288; i+=256){
        int oc = i >> 4, sg = i & 15;
        *(uint4*)(obase + (size_t)oc*HW + h*W + sg*8) = *(const uint4*)(ep + oc*132 + sg*8);
    }
}

// ---------------------------------------------------------------------------
// K3a: deform sampling + dw einsum via bf16 MFMA, NHWC feats.
// grid 2048 1-D, XCD swizzle. Writes dout2 NHWC [zb][h][px][oc].
// ---------------------------------------------------------------------------
__global__ __launch_bounds__(256,4) void k_deform_mfma(
    const bf16* __restrict__ feats2,
    const bf16* __restrict__ offs,
    const unsigned* __restrict__ dwb2,  // [n][oc][cp32] u32
    const float* __restrict__ db,
    bf16* __restrict__ dout2)
{
    int bid = blockIdx.x;
    int xcd  = bid & 7;
    int h    = (bid >> 3) & 127;
    int pass = bid >> 10;
    int zb   = xcd + 8*pass;

    int t = threadIdx.x;
    int px = t & 127, kh = t >> 7;
    int lane = t & 63, w = t >> 6;
    int l31 = lane & 31, half = lane >> 5;

    __shared__ unsigned Asu[4096];
    __shared__ unsigned Bsu[2304];

    const bf16* obase = offs + (size_t)zb*18*HW + h*W;
    const unsigned short* fbase = (const unsigned short*)(feats2 + (size_t)zb*FSL);

    f32x16 acc0, acc1;
    #pragma unroll
    for (int e=0;e<16;e++){ acc0[e]=0.f; acc1[e]=0.f; }

    for (int n=0; n<9; n++){
        float offy = b2f(obase[n*HW + px]);
        float offx = b2f(obase[(n+9)*HW + px]);
        float py  = (float)(h + n/3) + offy;
        float pxf = (float)(px + n%3) + offx;
        float fy = floorf(py), fx = floorf(pxf);
        float lty = fminf(fmaxf(fy,     0.f),129.f);
        float ltx = fminf(fmaxf(fx,     0.f),129.f);
        float rby = fminf(fmaxf(fy+1.f, 0.f),129.f);
        float rbx = fminf(fmaxf(fx+1.f, 0.f),129.f);
        float pyc = fminf(fmaxf(py,     0.f),129.f);
        float pxc = fminf(fmaxf(pxf,    0.f),129.f);
        float ay = 1.f + (lty-pyc), by = 1.f - (rby-pyc);
        float ax = 1.f + (ltx-pxc), bx = 1.f - (rbx-pxc);
        float glt = ay*ax, glb = ay*bx, grt = by*ax, grb = by*bx;
        int base = ((int)lty*XW + (int)ltx)*64;
        int dxo  = ((int)rbx - (int)ltx)*64;
        int dyo  = ((int)rby - (int)lty)*XW*64;

        const uint4* dsrc = (const uint4*)(dwb2 + n*2048);
        #pragma unroll
        for (int i=0;i<2;i++){
            int j = t + 256*i;
            int idx4 = j*4;
            int oc = idx4 >> 5, cp = idx4 & 31;
            *(uint4*)&Bsu[oc*36 + cp] = dsrc[j];
        }

        const unsigned short* fpx = fbase + base;
        #pragma unroll
        for (int u=0;u<2;u++){
            int sub = 2*kh + u;
            const unsigned short* fc = fpx + sub*16;
            unsigned LT[8], LB[8], RT[8], RB[8];
            *(uint4*)(LT)   = *(const uint4*)(fc);
            *(uint4*)(LT+4) = *(const uint4*)(fc+8);
            *(uint4*)(LB)   = *(const uint4*)(fc+dxo);
            *(uint4*)(LB+4) = *(const uint4*)(fc+dxo+8);
            *(uint4*)(RT)   = *(const uint4*)(fc+dyo);
            *(uint4*)(RT+4) = *(const uint4*)(fc+dyo+8);
            *(uint4*)(RB)   = *(const uint4*)(fc+dyo+dxo);
            *(uint4*)(RB+4) = *(const uint4*)(fc+dyo+dxo+8);
            unsigned pk[8];
            #pragma unroll
            for (int jq=0;jq<8;jq++){
                float2 a = up2(LT[jq]), bq = up2(LB[jq]);
                float2 c = up2(RT[jq]), dq = up2(RB[jq]);
                float slo = glt*a.x + glb*bq.x + grt*c.x + grb*dq.x;
                float shi = glt*a.y + glb*bq.y + grt*c.y + grb*dq.y;
                pk[jq] = pack2(slo, shi);
            }
            *(uint4*)&Asu[((sub*2+0)*128 + px)*4] = *(uint4*)pk;
            *(uint4*)&Asu[((sub*2+1)*128 + px)*4] = *(uint4*)(pk+4);
        }
        __syncthreads();
        const unsigned short* As16 = (const unsigned short*)Asu;
        const unsigned short* Bs16 = (const unsigned short*)Bsu;
        #pragma unroll
        for (int s=0;s<4;s++){
            s16x8 a  = *(const s16x8*)(As16 + ((s*2+half)*128 + 32*w + l31)*8);
            s16x8 b0 = *(const s16x8*)(Bs16 + (l31*36 + s*8 + half*4)*2);
            s16x8 b1 = *(const s16x8*)(Bs16 + ((32+l31)*36 + s*8 + half*4)*2);
            acc0 = __builtin_amdgcn_mfma_f32_32x32x16_bf16(a, b0, acc0, 0,0,0);
            acc1 = __builtin_amdgcn_mfma_f32_32x32x16_bf16(a, b1, acc1, 0,0,0);
        }
        __syncthreads();
    }

    unsigned short* ep = (unsigned short*)Asu;
    #pragma unroll
    for (int nt=0; nt<2; nt++){
        int oc = nt*32 + l31;
        float bias = db[oc];
        const f32x16& A = nt ? acc1 : acc0;
        #pragma unroll
        for (int rg=0; rg<4; rg++){
            int m0 = 32*w + 4*half + 8*rg;
            #pragma unroll
            for (int e=0;e<4;e++)
                ep[(m0+e)*64 + oc] = b16u(A[4*rg+e] + bias);
        }
    }
    __syncthreads();
    uint4* dst = (uint4*)((unsigned short*)dout2 + ((size_t)zb*128 + h)*(128*64));
    #pragma unroll
    for (int i=0;i<4;i++)
        dst[t + 256*i] = ((const uint4*)ep)[t + 256*i];
}

// ---------------------------------------------------------------------------
// K3b: 1x1 conv 256 -> 64 + cb + ReLU via bf16 MFMA. grid (128 h, 4 b).
// ---------------------------------------------------------------------------
__global__ __launch_bounds__(256,2) void k_combine_mfma(
    const bf16* __restrict__ dout2,
    const unsigned* __restrict__ cwb2,  // [oc][cp128] u32
    const float* __restrict__ cb,
    float* __restrict__ out)
{
    int h = blockIdx.x, b = blockIdx.y;
    int t = threadIdx.x;
    int px = t & 127, hf = t >> 7;
    int lane = t & 63, w = t >> 6, l31 = lane & 31, half = lane >> 5;

    __shared__ unsigned Bsu[64*132];
    __shared__ unsigned Asu2[1024];

    for (int i=t; i<8192; i+=256){
        int oc = i>>7, cp = i&127;
        Bsu[oc*132 + cp] = cwb2[i];
    }
    f32x16 acc0, acc1;
    #pragma unroll
    for (int e=0;e<16;e++){ acc0[e]=0.f; acc1[e]=0.f; }

    const unsigned short* dbase0 = (const unsigned short*)dout2;
    size_t rowsel = ((size_t)b*128 + h)*128 + px;
    uint4 v = *(const uint4*)(dbase0 + rowsel*64 + hf*8);
    for (int kc=0; kc<16; kc++){
        *(uint4*)&Asu2[(hf*128+px)*4] = v;
        __syncthreads();
        if (kc < 15){
            int kn = kc+1;
            int d = kn>>2, c16 = kn&3;
            v = *(const uint4*)(dbase0 + ((size_t)d*4*128*128*64 + rowsel*64) + c16*16 + hf*8);
        }
        const unsigned short* As16 = (const unsigned short*)Asu2;
        const unsigned short* Bs16 = (const unsigned short*)Bsu;
        s16x8 a  = *(const s16x8*)(As16 + (half*128 + 32*w + l31)*8);
        s16x8 b0 = *(const s16x8*)(Bs16 + (l31*132 + kc*8 + half*4)*2);
        s16x8 b1 = *(const s16x8*)(Bs16 + ((32+l31)*132 + kc*8 + half*4)*2);
        acc0 = __builtin_amdgcn_mfma_f32_32x32x16_bf16(a, b0, acc0, 0,0,0);
        acc1 = __builtin_amdgcn_mfma_f32_32x32x16_bf16(a, b1, acc1, 0,0,0);
        __syncthreads();
    }
    float* ep = (float*)Bsu;
    #pragma unroll
    for (int nt=0; nt<2; nt++){
        int oc = nt*32 + l31;
        float bias = cb[oc];
        const f32x16& A = nt ? acc1 : acc0;
        #pragma unroll
        for (int rg=0; rg<4; rg++){
            int m0 = 32*w + 4*half + 8*rg;
            #pragma unroll
            for (int e=0;e<4;e++)
                ep[oc*132 + m0+e] = fmaxf(A[4*rg+e] + bias, 0.f);
        }
    }
    __syncthreads();
    for (int i=t; i<2048; i+=256){
        int oc = i>>5, sg = i&31;
        *(uint4*)&out[(((size_t)b*64+oc)*128 + h)*128 + sg*4] = *(const uint4*)&ep[oc*132 + sg*4];
    }
}

extern "C" void kernel_launch(void* const* d_in, const int* in_sizes, int n_in,
                              void* d_out, int out_size, void* d_ws, size_t ws_size,
                              hipStream_t stream) {
    const float* x  = (const float*)d_in[0];
    const float* w1 = (const float*)d_in[1];
    const float* b1 = (const float*)d_in[2];
    const float* w2 = (const float*)d_in[3];
    const float* b2 = (const float*)d_in[4];
    const float* w3 = (const float*)d_in[5];
    const float* b3 = (const float*)d_in[6];
    const float* w4 = (const float*)d_in[7];
    const float* b4 = (const float*)d_in[8];
    const float* pw = (const float*)d_in[9];
    const float* pb = (const float*)d_in[10];
    const float* dw = (const float*)d_in[11];
    const float* db = (const float*)d_in[12];
    const float* cw = (const float*)d_in[13];
    const float* cb = (const float*)d_in[14];
    float* out = (float*)d_out;

    bf16* feats2 = (bf16*)d_ws;                             // 34.6 MB
    bf16* offs   = feats2 + (size_t)16*FSL;                 // 9.4 MB
    bf16* region2 = offs + (size_t)16*18*HW;
    bf16* dout2  = region2;                                 // 33.55 MB
    unsigned* xt  = (unsigned*)region2;                     // 21.2 MB (dead before dout2)
    unsigned* wbt = xt + (size_t)4*8*XTD*XTD*8;             // 0.59 MB (dead before dout2)
    unsigned* dwb2 = (unsigned*)(dout2 + (size_t)16*128*128*64);  // 73.7 KB
    unsigned* cwb2 = dwb2 + 18432;                          // 32.8 KB
    unsigned* pwb  = cwb2 + 8192;                           // 36.9 KB

    k_prep        <<<dim3(1740),    256, 0, stream>>>(w1,w2,w3,w4, dw, cw, pw,
                                                      (uint4*)xt, wbt, dwb2, cwb2, pwb);
    k_xprep       <<<dim3(128,4),   256, 0, stream>>>(x, xt);
    k_branch_mfma <<<dim3(1024),    256, 0, stream>>>(xt, wbt, b1,b2,b3,b4, feats2);
    k_offset_mfma <<<dim3(2048),    256, 0, stream>>>(feats2, pwb, pb, offs);
    k_deform_mfma <<<dim3(2048),    256, 0, stream>>>(feats2, offs, dwb2, db, dout2);
    k_combine_mfma<<<dim3(128,4),   256, 0, stream>>>(dout2, cwb2, cb, out);
}